// Round 1
// baseline (631.027 us; speedup 1.0000x reference)
//
#include <hip/hip_runtime.h>
#include <math.h>

#define N_NODES 50000
#define N_EDGES 500000
#define HIDDEN 128
#define HEADS 8
#define HEAD_DIM 16

// workspace layout, element offsets (4-byte units)
#define OFF_Q       0u          // 6,400,000 floats
#define OFF_K       6400000u    // 6,400,000 floats (reused as h_upd)
#define OFF_V       12800000u   // 6,400,000 floats
#define OFF_LG      19200000u   // 4,000,000 floats
#define OFF_DISP    23200000u   // 150,000 floats
#define OFF_CNT     23350016u   // 50,000 ints
#define OFF_ROWPTR  23400032u   // 50,001 ints
#define OFF_CURSOR  23450048u   // 50,000 ints
#define OFF_ESORT   23500064u   // 500,000 ints
// total ~ 96 MB

__global__ void k_zero_int(int* __restrict__ p, int n) {
    int i = blockIdx.x * 256 + threadIdx.x;
    if (i < n) p[i] = 0;
}

// q/k/v = h @ W{q,k,v} + b.  Block: 256 threads, 16 rows.
// col = tid&127 (coalesced W reads); each thread accumulates 8 rows.
// h row values are wave-uniform -> forced scalar loads via readfirstlane.
__global__ __launch_bounds__(256) void k_qkv(
    const float* __restrict__ h,
    const float* __restrict__ Wq, const float* __restrict__ bq,
    const float* __restrict__ Wk, const float* __restrict__ bk,
    const float* __restrict__ Wv, const float* __restrict__ bv,
    float* __restrict__ q, float* __restrict__ k, float* __restrict__ v) {
    const int col  = threadIdx.x & 127;
    const int rgrp = __builtin_amdgcn_readfirstlane(threadIdx.x >> 7);
    const int row0 = blockIdx.x * 16 + rgrp * 8;
    float aq[8] = {0}, ak[8] = {0}, av[8] = {0};
    for (int k0 = 0; k0 < HIDDEN; k0 += 4) {
        float wq[4], wk[4], wv[4];
#pragma unroll
        for (int j = 0; j < 4; ++j) {
            wq[j] = Wq[(k0 + j) * HIDDEN + col];
            wk[j] = Wk[(k0 + j) * HIDDEN + col];
            wv[j] = Wv[(k0 + j) * HIDDEN + col];
        }
#pragma unroll
        for (int r = 0; r < 8; ++r) {
            const float* hp = h + (size_t)(row0 + r) * HIDDEN + k0;
            float h0 = hp[0], h1 = hp[1], h2 = hp[2], h3 = hp[3];
            aq[r] += h0 * wq[0] + h1 * wq[1] + h2 * wq[2] + h3 * wq[3];
            ak[r] += h0 * wk[0] + h1 * wk[1] + h2 * wk[2] + h3 * wk[3];
            av[r] += h0 * wv[0] + h1 * wv[1] + h2 * wv[2] + h3 * wv[3];
        }
    }
    const float bq_ = bq[col], bk_ = bk[col], bv_ = bv[col];
#pragma unroll
    for (int r = 0; r < 8; ++r) {
        size_t o = (size_t)(row0 + r) * HIDDEN + col;
        q[o] = aq[r] + bq_;
        k[o] = ak[r] + bk_;
        v[o] = av[r] + bv_;
    }
}

// one thread per (edge, head): lg = q[src].k[dst]/4 - (d^2*Wd + bd)
__global__ __launch_bounds__(256) void k_edge(
    const float* __restrict__ q, const float* __restrict__ k,
    const int* __restrict__ src, const int* __restrict__ dst,
    const float* __restrict__ dist,
    const float* __restrict__ Wd, const float* __restrict__ bd,
    float* __restrict__ lg) {
    int t = blockIdx.x * 256 + threadIdx.x;   // grid exact: E*8 threads
    int e = t >> 3, hd = t & 7;
    int s = src[e], d = dst[e];
    const float4* qp = (const float4*)(q + (size_t)s * HIDDEN + hd * HEAD_DIM);
    const float4* kp = (const float4*)(k + (size_t)d * HIDDEN + hd * HEAD_DIM);
    float dot = 0.f;
#pragma unroll
    for (int j = 0; j < 4; ++j) {
        float4 a = qp[j], b = kp[j];
        dot += a.x * b.x + a.y * b.y + a.z * b.z + a.w * b.w;
    }
    float dd = dist[e];
    lg[(size_t)e * 8 + hd] = dot * 0.25f - (dd * dd * Wd[hd] + bd[hd]);
}

__global__ void k_count(const int* __restrict__ src, int* __restrict__ cnt) {
    int e = blockIdx.x * 256 + threadIdx.x;
    if (e < N_EDGES) atomicAdd(&cnt[src[e]], 1);
}

// single-block scan over 50000 counts -> rowptr (inclusive shifted) + cursor (exclusive)
__global__ __launch_bounds__(1024) void k_scan(const int* __restrict__ cnt,
                                               int* __restrict__ rowptr,
                                               int* __restrict__ cursor, int n) {
    __shared__ int buf[1024];
    __shared__ int carry;
    int t = threadIdx.x;
    if (t == 0) carry = 0;
    __syncthreads();
    for (int base = 0; base < n; base += 1024) {
        int i = base + t;
        int val = (i < n) ? cnt[i] : 0;
        buf[t] = val;
        __syncthreads();
        for (int off = 1; off < 1024; off <<= 1) {
            int a = (t >= off) ? buf[t - off] : 0;
            __syncthreads();
            buf[t] += a;
            __syncthreads();
        }
        int incl = buf[t] + carry;
        if (i < n) { rowptr[i + 1] = incl; cursor[i] = incl - val; }
        __syncthreads();
        if (t == 1023) carry = incl;
        __syncthreads();
    }
    if (t == 0) rowptr[0] = 0;
}

__global__ void k_scatter(const int* __restrict__ src, int* __restrict__ cursor,
                          int* __restrict__ esort) {
    int e = blockIdx.x * 256 + threadIdx.x;
    if (e < N_EDGES) {
        int pos = atomicAdd(&cursor[src[e]], 1);
        esort[pos] = e;
    }
}

// one wave per node: segment softmax (max, sum) over its edges, then
// weighted accumulation of v[dst] into h_upd and displacement into disp.
__global__ __launch_bounds__(256) void k_node(
    const float* __restrict__ lg, const float* __restrict__ v,
    const float* __restrict__ x, const int* __restrict__ dst,
    const int* __restrict__ esort, const int* __restrict__ rowptr,
    float* __restrict__ hupd, float* __restrict__ disp) {
    int wave = threadIdx.x >> 6, lane = threadIdx.x & 63;
    int node = blockIdx.x * 4 + wave;                 // grid exact: N/4 blocks
    int beg = rowptr[node], end = rowptr[node + 1];
    int hd = lane & 7, eslot = lane >> 3;

    // pass 1: per-head max (lane handles head hd, edge slots eslot, eslot+8, ...)
    float mx = -3.0e38f;
    for (int p = beg + eslot; p < end; p += 8) {
        int e = esort[p];
        mx = fmaxf(mx, lg[(size_t)e * 8 + hd]);
    }
    mx = fmaxf(mx, __shfl_xor(mx, 8));
    mx = fmaxf(mx, __shfl_xor(mx, 16));
    mx = fmaxf(mx, __shfl_xor(mx, 32));

    // pass 2: per-head sum of exp
    float sm = 0.f;
    for (int p = beg + eslot; p < end; p += 8) {
        int e = esort[p];
        sm += __expf(lg[(size_t)e * 8 + hd] - mx);
    }
    sm += __shfl_xor(sm, 8);
    sm += __shfl_xor(sm, 16);
    sm += __shfl_xor(sm, 32);

    // pass 3: lane covers dims 2*lane, 2*lane+1 -> head hp = lane>>3
    int hp = lane >> 3;
    float m3  = __shfl(mx, hp);   // lane h holds stats of head h (h<8)
    float s3  = __shfl(sm, hp);
    float inv = 1.f / fmaxf(s3, 1e-9f);
    float xs  = (lane < 3) ? x[node * 3 + lane] : 0.f;
    float acc0 = 0.f, acc1 = 0.f, da = 0.f;
    for (int p = beg; p < end; ++p) {
        int e = esort[p];
        int d = dst[e];
        float w = __expf(lg[(size_t)e * 8 + hp] - m3) * inv;
        const float2 vv = *(const float2*)(v + (size_t)d * HIDDEN + 2 * lane);
        acc0 += vv.x * w;
        acc1 += vv.y * w;
        // wave-sum of w = 8 * sum_h w_h  ->  w_mean = wave_sum/64
        float wsum = w;
        wsum += __shfl_xor(wsum, 1);  wsum += __shfl_xor(wsum, 2);
        wsum += __shfl_xor(wsum, 4);  wsum += __shfl_xor(wsum, 8);
        wsum += __shfl_xor(wsum, 16); wsum += __shfl_xor(wsum, 32);
        if (lane < 3) da += (x[d * 3 + lane] - xs) * (wsum * 0.015625f);
    }
    float2 o; o.x = acc0; o.y = acc1;
    *(float2*)(hupd + (size_t)node * HIDDEN + 2 * lane) = o;
    if (lane < 3) disp[node * 3 + lane] = da;
}

// h_out = h + h_upd @ Wo + bo
__global__ __launch_bounds__(256) void k_hout(
    const float* __restrict__ h, const float* __restrict__ hupd,
    const float* __restrict__ Wo, const float* __restrict__ bo,
    float* __restrict__ hout) {
    const int col  = threadIdx.x & 127;
    const int rgrp = __builtin_amdgcn_readfirstlane(threadIdx.x >> 7);
    const int row0 = blockIdx.x * 16 + rgrp * 8;
    float acc[8] = {0};
    for (int k0 = 0; k0 < HIDDEN; k0 += 4) {
        float w[4];
#pragma unroll
        for (int j = 0; j < 4; ++j) w[j] = Wo[(k0 + j) * HIDDEN + col];
#pragma unroll
        for (int r = 0; r < 8; ++r) {
            const float* hp = hupd + (size_t)(row0 + r) * HIDDEN + k0;
            acc[r] += hp[0] * w[0] + hp[1] * w[1] + hp[2] * w[2] + hp[3] * w[3];
        }
    }
    const float bo_ = bo[col];
#pragma unroll
    for (int r = 0; r < 8; ++r) {
        size_t o = (size_t)(row0 + r) * HIDDEN + col;
        hout[o] = h[o] + acc[r] + bo_;
    }
}

// t1 = silu(h_out @ Wg1 + bg1)
__global__ __launch_bounds__(256) void k_gate1(
    const float* __restrict__ hout, const float* __restrict__ Wg1,
    const float* __restrict__ bg1, float* __restrict__ t1) {
    const int col  = threadIdx.x & 127;
    const int rgrp = __builtin_amdgcn_readfirstlane(threadIdx.x >> 7);
    const int row0 = blockIdx.x * 16 + rgrp * 8;
    float acc[8] = {0};
    for (int k0 = 0; k0 < HIDDEN; k0 += 4) {
        float w[4];
#pragma unroll
        for (int j = 0; j < 4; ++j) w[j] = Wg1[(k0 + j) * HIDDEN + col];
#pragma unroll
        for (int r = 0; r < 8; ++r) {
            const float* hp = hout + (size_t)(row0 + r) * HIDDEN + k0;
            acc[r] += hp[0] * w[0] + hp[1] * w[1] + hp[2] * w[2] + hp[3] * w[3];
        }
    }
    const float b_ = bg1[col];
#pragma unroll
    for (int r = 0; r < 8; ++r) {
        float z = acc[r] + b_;
        t1[(size_t)(row0 + r) * HIDDEN + col] = z / (1.f + __expf(-z));
    }
}

// gate = tanh(t1 . Wg2 + bg2);  x_out = x + gate * disp   (one wave per row)
__global__ __launch_bounds__(256) void k_gate2(
    const float* __restrict__ t1, const float* __restrict__ Wg2,
    const float* __restrict__ bg2, const float* __restrict__ x,
    const float* __restrict__ disp, float* __restrict__ xout) {
    int wave = threadIdx.x >> 6, lane = threadIdx.x & 63;
    int row = blockIdx.x * 4 + wave;                  // grid exact: N/4 blocks
    float p = t1[(size_t)row * HIDDEN + lane] * Wg2[lane]
            + t1[(size_t)row * HIDDEN + 64 + lane] * Wg2[64 + lane];
    p += __shfl_xor(p, 1);  p += __shfl_xor(p, 2);  p += __shfl_xor(p, 4);
    p += __shfl_xor(p, 8);  p += __shfl_xor(p, 16); p += __shfl_xor(p, 32);
    float g = tanhf(p + bg2[0]);
    if (lane < 3) {
        int o = row * 3 + lane;
        xout[o] = x[o] + g * disp[o];
    }
}

extern "C" void kernel_launch(void* const* d_in, const int* in_sizes, int n_in,
                              void* d_out, int out_size, void* d_ws, size_t ws_size,
                              hipStream_t stream) {
    const float* h    = (const float*)d_in[0];
    const float* x    = (const float*)d_in[1];
    const int*   src  = (const int*)d_in[2];
    const int*   dst  = (const int*)d_in[3];
    const float* dist = (const float*)d_in[4];
    const float* Wq = (const float*)d_in[5];  const float* bq = (const float*)d_in[6];
    const float* Wk = (const float*)d_in[7];  const float* bk = (const float*)d_in[8];
    const float* Wv = (const float*)d_in[9];  const float* bv = (const float*)d_in[10];
    const float* Wo = (const float*)d_in[11]; const float* bo = (const float*)d_in[12];
    const float* Wd = (const float*)d_in[13]; const float* bd = (const float*)d_in[14];
    const float* Wg1 = (const float*)d_in[15]; const float* bg1 = (const float*)d_in[16];
    const float* Wg2 = (const float*)d_in[17]; const float* bg2 = (const float*)d_in[18];

    float* ws   = (float*)d_ws;
    float* q    = ws + OFF_Q;
    float* kk   = ws + OFF_K;
    float* vv   = ws + OFF_V;
    float* lg   = ws + OFF_LG;
    float* disp = ws + OFF_DISP;
    int* cnt    = (int*)(ws + OFF_CNT);
    int* rowptr = (int*)(ws + OFF_ROWPTR);
    int* cursor = (int*)(ws + OFF_CURSOR);
    int* esort  = (int*)(ws + OFF_ESORT);
    float* hupd = kk;   // k consumed by k_edge before k_node writes here
    float* t1   = q;    // q consumed by k_edge before k_gate1 writes here
    float* hout = (float*)d_out;
    float* xout = hout + (size_t)N_NODES * HIDDEN;

    k_zero_int<<<(N_NODES + 255) / 256, 256, 0, stream>>>(cnt, N_NODES);
    k_qkv<<<N_NODES / 16, 256, 0, stream>>>(h, Wq, bq, Wk, bk, Wv, bv, q, kk, vv);
    k_edge<<<(N_EDGES * 8) / 256, 256, 0, stream>>>(q, kk, src, dst, dist, Wd, bd, lg);
    k_count<<<(N_EDGES + 255) / 256, 256, 0, stream>>>(src, cnt);
    k_scan<<<1, 1024, 0, stream>>>(cnt, rowptr, cursor, N_NODES);
    k_scatter<<<(N_EDGES + 255) / 256, 256, 0, stream>>>(src, cursor, esort);
    k_node<<<N_NODES / 4, 256, 0, stream>>>(lg, vv, x, dst, esort, rowptr, hupd, disp);
    k_hout<<<N_NODES / 16, 256, 0, stream>>>(h, hupd, Wo, bo, hout);
    k_gate1<<<N_NODES / 16, 256, 0, stream>>>(hout, Wg1, bg1, t1);
    k_gate2<<<N_NODES / 4, 256, 0, stream>>>(t1, Wg2, bg2, x, disp, xout);
}

// Round 2
// 471.081 us; speedup vs baseline: 1.3395x; 1.3395x over previous
//
#include <hip/hip_runtime.h>
#include <math.h>

#define N_NODES 50000
#define N_EDGES 500000
#define HIDDEN 128
#define HEADS 8
#define HEAD_DIM 16

// workspace layout, element offsets (4-byte units)
#define OFF_Q       0u          // 6,400,000 floats (freed after k_edge; reused for dsort/loc/bsum)
#define OFF_K       6400000u    // 6,400,000 floats (freed after k_edge; reused as h_upd)
#define OFF_V       12800000u   // 6,400,000 floats
#define OFF_LG      19200000u   // 4,000,000 floats
#define OFF_DISP    23200000u   // 150,000 floats
#define OFF_CNT     23350016u   // 50,000 ints
#define OFF_ROWPTR  23400032u   // 50,001 ints
#define OFF_CURSOR  23450048u   // 50,000 ints
#define OFF_ESORT   23500064u   // 500,000 ints
// end: 24,000,064 floats = 96.0 MB (same footprint as round 1)

__global__ void k_zero_int(int* __restrict__ p, int n) {
    int i = blockIdx.x * 256 + threadIdx.x;
    if (i < n) p[i] = 0;
}

// q/k/v = h @ W{q,k,v} + b.  Block: 256 threads, 16 rows.
__global__ __launch_bounds__(256) void k_qkv(
    const float* __restrict__ h,
    const float* __restrict__ Wq, const float* __restrict__ bq,
    const float* __restrict__ Wk, const float* __restrict__ bk,
    const float* __restrict__ Wv, const float* __restrict__ bv,
    float* __restrict__ q, float* __restrict__ k, float* __restrict__ v) {
    const int col  = threadIdx.x & 127;
    const int rgrp = __builtin_amdgcn_readfirstlane(threadIdx.x >> 7);
    const int row0 = blockIdx.x * 16 + rgrp * 8;
    float aq[8] = {0}, ak[8] = {0}, av[8] = {0};
    for (int k0 = 0; k0 < HIDDEN; k0 += 4) {
        float wq[4], wk[4], wv[4];
#pragma unroll
        for (int j = 0; j < 4; ++j) {
            wq[j] = Wq[(k0 + j) * HIDDEN + col];
            wk[j] = Wk[(k0 + j) * HIDDEN + col];
            wv[j] = Wv[(k0 + j) * HIDDEN + col];
        }
#pragma unroll
        for (int r = 0; r < 8; ++r) {
            const float* hp = h + (size_t)(row0 + r) * HIDDEN + k0;
            float h0 = hp[0], h1 = hp[1], h2 = hp[2], h3 = hp[3];
            aq[r] += h0 * wq[0] + h1 * wq[1] + h2 * wq[2] + h3 * wq[3];
            ak[r] += h0 * wk[0] + h1 * wk[1] + h2 * wk[2] + h3 * wk[3];
            av[r] += h0 * wv[0] + h1 * wv[1] + h2 * wv[2] + h3 * wv[3];
        }
    }
    const float bq_ = bq[col], bk_ = bk[col], bv_ = bv[col];
#pragma unroll
    for (int r = 0; r < 8; ++r) {
        size_t o = (size_t)(row0 + r) * HIDDEN + col;
        q[o] = aq[r] + bq_;
        k[o] = ak[r] + bk_;
        v[o] = av[r] + bv_;
    }
}

// one thread per (edge, head): lg = q[src].k[dst]/4 - (d^2*Wd + bd)
// fused: per-edge degree count (head-0 lane).
__global__ __launch_bounds__(256) void k_edge(
    const float* __restrict__ q, const float* __restrict__ k,
    const int* __restrict__ src, const int* __restrict__ dst,
    const float* __restrict__ dist,
    const float* __restrict__ Wd, const float* __restrict__ bd,
    float* __restrict__ lg, int* __restrict__ cnt) {
    int t = blockIdx.x * 256 + threadIdx.x;   // grid exact: E*8 threads
    int e = t >> 3, hd = t & 7;
    int s = src[e], d = dst[e];
    const float4* qp = (const float4*)(q + (size_t)s * HIDDEN + hd * HEAD_DIM);
    const float4* kp = (const float4*)(k + (size_t)d * HIDDEN + hd * HEAD_DIM);
    float dot = 0.f;
#pragma unroll
    for (int j = 0; j < 4; ++j) {
        float4 a = qp[j], b = kp[j];
        dot += a.x * b.x + a.y * b.y + a.z * b.z + a.w * b.w;
    }
    float dd = dist[e];
    lg[(size_t)e * 8 + hd] = dot * 0.25f - (dd * dd * Wd[hd] + bd[hd]);
    if (hd == 0) atomicAdd(&cnt[s], 1);
}

// hierarchical scan over 50000 counts
__global__ __launch_bounds__(1024) void k_scan1(const int* __restrict__ cnt,
                                                int* __restrict__ loc,
                                                int* __restrict__ bsum, int n) {
    __shared__ int buf[1024];
    int t = threadIdx.x;
    int i = blockIdx.x * 1024 + t;
    int val = (i < n) ? cnt[i] : 0;
    buf[t] = val;
    __syncthreads();
    for (int off = 1; off < 1024; off <<= 1) {
        int a = (t >= off) ? buf[t - off] : 0;
        __syncthreads();
        buf[t] += a;
        __syncthreads();
    }
    if (i < n) loc[i] = buf[t];               // inclusive local scan
    if (t == 1023) bsum[blockIdx.x] = buf[1023];
}

__global__ void k_scan2(int* __restrict__ bsum, int nb) {   // 1 block, 64 threads
    int t = threadIdx.x;
    int v = (t < nb) ? bsum[t] : 0;
    for (int off = 1; off < 64; off <<= 1) {
        int a = __shfl_up(v, off);
        if (t >= off) v += a;
    }
    if (t < nb) bsum[t] = v;                  // inclusive scan of block sums
}

__global__ void k_scan3(const int* __restrict__ cnt, const int* __restrict__ loc,
                        const int* __restrict__ bsum,
                        int* __restrict__ rowptr, int* __restrict__ cursor, int n) {
    int i = blockIdx.x * 256 + threadIdx.x;
    if (i < n) {
        int off = (i >= 1024) ? bsum[(i >> 10) - 1] : 0;
        int incl = loc[i] + off;
        rowptr[i + 1] = incl;
        cursor[i] = incl - cnt[i];
    }
    if (i == 0) rowptr[0] = 0;
}

// scatter edge ids into CSR order; also pre-gather dst to kill the
// dependent dst[] load in k_node.
__global__ void k_scatter(const int* __restrict__ src, const int* __restrict__ dst,
                          int* __restrict__ cursor,
                          int* __restrict__ esort, int* __restrict__ dsort) {
    int e = blockIdx.x * 256 + threadIdx.x;
    if (e < N_EDGES) {
        int pos = atomicAdd(&cursor[src[e]], 1);
        esort[pos] = e;
        dsort[pos] = dst[e];
    }
}

// one wave per node: lane-per-edge softmax stats (register lg rows,
// butterfly reductions), unnormalized weights staged in LDS, then a
// tight accumulate loop of independent v-gathers. General for any degree
// via 64-edge chunks.
__global__ __launch_bounds__(256) void k_node(
    const float* __restrict__ lg, const float* __restrict__ v,
    const float* __restrict__ x,
    const int* __restrict__ esort, const int* __restrict__ dsort,
    const int* __restrict__ rowptr,
    float* __restrict__ hupd, float* __restrict__ disp) {
    __shared__ float wbuf_all[4][512];        // [wave][head*64 + edge]
    const int wave = threadIdx.x >> 6, lane = threadIdx.x & 63;
    float* wbuf = wbuf_all[wave];
    const int node = blockIdx.x * 4 + wave;   // grid exact: N/4 blocks
    const int beg = rowptr[node], end = rowptr[node + 1];

    // ---- pass A: per-head max ----
    float m[8];
#pragma unroll
    for (int j = 0; j < 8; ++j) m[j] = -3.0e38f;
    for (int cb = beg; cb < end; cb += 64) {
        int idx = cb + lane;
        if (idx < end) {
            int e = esort[idx];
            const float4* lp = (const float4*)(lg + (size_t)e * 8);
            float4 a = lp[0], b = lp[1];
            m[0] = fmaxf(m[0], a.x); m[1] = fmaxf(m[1], a.y);
            m[2] = fmaxf(m[2], a.z); m[3] = fmaxf(m[3], a.w);
            m[4] = fmaxf(m[4], b.x); m[5] = fmaxf(m[5], b.y);
            m[6] = fmaxf(m[6], b.z); m[7] = fmaxf(m[7], b.w);
        }
    }
    for (int off = 1; off < 64; off <<= 1) {
#pragma unroll
        for (int j = 0; j < 8; ++j) m[j] = fmaxf(m[j], __shfl_xor(m[j], off));
    }

    // ---- pass B+C per chunk: exp, stage to LDS, accumulate ----
    float s[8];
#pragma unroll
    for (int j = 0; j < 8; ++j) s[j] = 0.f;
    const int hp  = lane >> 3;   // head for acc lanes (dims 2*lane, 2*lane+1)
    const int hq  = lane & 7;    // head for da lanes
    const int dim = lane >> 3;   // dim for da lanes (valid when <3, lanes 0..23)
    float xs = 0.f;
    if (lane < 24) xs = x[node * 3 + dim];
    float acc0 = 0.f, acc1 = 0.f, da = 0.f;

    for (int cb = beg; cb < end; cb += 64) {
        int idx = cb + lane;
        int clen = min(64, end - cb);
        int d = 0;
        if (idx < end) {
            int e = esort[idx];
            d = dsort[idx];
            const float4* lp = (const float4*)(lg + (size_t)e * 8);
            float4 a = lp[0], b = lp[1];
            float wv[8];
            wv[0] = __expf(a.x - m[0]); wv[1] = __expf(a.y - m[1]);
            wv[2] = __expf(a.z - m[2]); wv[3] = __expf(a.w - m[3]);
            wv[4] = __expf(b.x - m[4]); wv[5] = __expf(b.y - m[5]);
            wv[6] = __expf(b.z - m[6]); wv[7] = __expf(b.w - m[7]);
#pragma unroll
            for (int j = 0; j < 8; ++j) {
                s[j] += wv[j];
                wbuf[j * 64 + lane] = wv[j];
            }
        }
        // same-wave LDS producer->consumer: drain LDS queue, block reordering
        __asm__ volatile("s_waitcnt lgkmcnt(0)" ::: "memory");
        for (int i = 0; i < clen; ++i) {
            int di = __shfl(d, i);
            float wa = wbuf[hp * 64 + i];
            const float2 vv = *(const float2*)(v + (size_t)di * HIDDEN + 2 * lane);
            acc0 += vv.x * wa;
            acc1 += vv.y * wa;
            if (lane < 24) {
                float wd = wbuf[hq * 64 + i];
                da += (x[di * 3 + dim] - xs) * wd;
            }
        }
        __asm__ volatile("" ::: "memory");   // keep chunk iterations ordered vs LDS reuse
    }

    // ---- epilogue ----
    for (int off = 1; off < 64; off <<= 1) {
#pragma unroll
        for (int j = 0; j < 8; ++j) s[j] += __shfl_xor(s[j], off);
    }
    float inva = 1.f / fmaxf(s[hp], 1e-9f);
    float2 o; o.x = acc0 * inva; o.y = acc1 * inva;
    *(float2*)(hupd + (size_t)node * HIDDEN + 2 * lane) = o;
    if (lane < 24) da *= 0.125f / fmaxf(s[hq], 1e-9f);
    da += __shfl_xor(da, 1);
    da += __shfl_xor(da, 2);
    da += __shfl_xor(da, 4);
    if (lane < 24 && hq == 0) disp[node * 3 + dim] = da;
}

// fused: h_out = h + h_upd @ Wo + bo ; t1 = silu(h_out @ Wg1 + bg1) (in LDS);
// gate = tanh(t1 . Wg2 + bg2) ; x_out = x + gate * disp
__global__ __launch_bounds__(256) void k_hout_gate(
    const float* __restrict__ h, const float* __restrict__ hupd,
    const float* __restrict__ Wo, const float* __restrict__ bo,
    const float* __restrict__ Wg1, const float* __restrict__ bg1,
    const float* __restrict__ Wg2, const float* __restrict__ bg2,
    const float* __restrict__ x, const float* __restrict__ disp,
    float* __restrict__ hout, float* __restrict__ xout) {
    __shared__ float hb[16 * 128];
    __shared__ float red[4][8];
    const int col  = threadIdx.x & 127;
    const int rgrp = __builtin_amdgcn_readfirstlane(threadIdx.x >> 7);
    const int row0 = blockIdx.x * 16 + rgrp * 8;

    // GEMM 1: hout
    float acc[8] = {0};
    for (int k0 = 0; k0 < HIDDEN; k0 += 4) {
        float w[4];
#pragma unroll
        for (int j = 0; j < 4; ++j) w[j] = Wo[(k0 + j) * HIDDEN + col];
#pragma unroll
        for (int r = 0; r < 8; ++r) {
            const float* hp = hupd + (size_t)(row0 + r) * HIDDEN + k0;
            acc[r] += hp[0] * w[0] + hp[1] * w[1] + hp[2] * w[2] + hp[3] * w[3];
        }
    }
    const float bo_ = bo[col];
#pragma unroll
    for (int r = 0; r < 8; ++r) {
        size_t oo = (size_t)(row0 + r) * HIDDEN + col;
        float val = h[oo] + acc[r] + bo_;
        hout[oo] = val;
        hb[(rgrp * 8 + r) * 128 + col] = val;
    }
    __syncthreads();

    // GEMM 2: silu(hout @ Wg1 + bg1) * Wg2[col], reduced over cols
    float acc2[8] = {0};
    for (int k0 = 0; k0 < HIDDEN; k0 += 4) {
        float w[4];
#pragma unroll
        for (int j = 0; j < 4; ++j) w[j] = Wg1[(k0 + j) * HIDDEN + col];
#pragma unroll
        for (int r = 0; r < 8; ++r) {
            const float* hp = hb + (rgrp * 8 + r) * 128 + k0;
            acc2[r] += hp[0] * w[0] + hp[1] * w[1] + hp[2] * w[2] + hp[3] * w[3];
        }
    }
    const float bg1_ = bg1[col];
    const float w2 = Wg2[col];
    float p[8];
#pragma unroll
    for (int r = 0; r < 8; ++r) {
        float z = acc2[r] + bg1_;
        p[r] = (z / (1.f + __expf(-z))) * w2;
    }
    for (int off = 1; off < 64; off <<= 1) {
#pragma unroll
        for (int r = 0; r < 8; ++r) p[r] += __shfl_xor(p[r], off);
    }
    const int wavei = threadIdx.x >> 6, lane = threadIdx.x & 63;
    if (lane == 0) {
#pragma unroll
        for (int r = 0; r < 8; ++r) red[wavei][r] = p[r];
    }
    __syncthreads();
    int t = threadIdx.x;
    if (t < 16) {
        int rg = t >> 3, r = t & 7;
        float sum = red[rg * 2][r] + red[rg * 2 + 1][r];
        float g = tanhf(sum + bg2[0]);
        int row = blockIdx.x * 16 + t;
#pragma unroll
        for (int dd = 0; dd < 3; ++dd) {
            int oo = row * 3 + dd;
            xout[oo] = x[oo] + g * disp[oo];
        }
    }
}

extern "C" void kernel_launch(void* const* d_in, const int* in_sizes, int n_in,
                              void* d_out, int out_size, void* d_ws, size_t ws_size,
                              hipStream_t stream) {
    const float* h    = (const float*)d_in[0];
    const float* x    = (const float*)d_in[1];
    const int*   src  = (const int*)d_in[2];
    const int*   dst  = (const int*)d_in[3];
    const float* dist = (const float*)d_in[4];
    const float* Wq = (const float*)d_in[5];  const float* bq = (const float*)d_in[6];
    const float* Wk = (const float*)d_in[7];  const float* bk = (const float*)d_in[8];
    const float* Wv = (const float*)d_in[9];  const float* bv = (const float*)d_in[10];
    const float* Wo = (const float*)d_in[11]; const float* bo = (const float*)d_in[12];
    const float* Wd = (const float*)d_in[13]; const float* bd = (const float*)d_in[14];
    const float* Wg1 = (const float*)d_in[15]; const float* bg1 = (const float*)d_in[16];
    const float* Wg2 = (const float*)d_in[17]; const float* bg2 = (const float*)d_in[18];

    float* ws   = (float*)d_ws;
    float* q    = ws + OFF_Q;
    float* kk   = ws + OFF_K;
    float* vv   = ws + OFF_V;
    float* lg   = ws + OFF_LG;
    float* disp = ws + OFF_DISP;
    int* cnt    = (int*)(ws + OFF_CNT);
    int* rowptr = (int*)(ws + OFF_ROWPTR);
    int* cursor = (int*)(ws + OFF_CURSOR);
    int* esort  = (int*)(ws + OFF_ESORT);
    // q region is dead after k_edge -> reuse for scan scratch + dsort
    int* dsort  = (int*)(ws + OFF_Q);             // 500,000 ints
    int* loc    = (int*)(ws + OFF_Q + 500000u);   // 50,000 ints
    int* bsum   = (int*)(ws + OFF_Q + 550000u);   // 64 ints
    float* hupd = kk;     // k region dead after k_edge
    float* hout = (float*)d_out;
    float* xout = hout + (size_t)N_NODES * HIDDEN;

    const int nscan = (N_NODES + 1023) / 1024;    // 49

    k_zero_int<<<(N_NODES + 255) / 256, 256, 0, stream>>>(cnt, N_NODES);
    k_qkv<<<N_NODES / 16, 256, 0, stream>>>(h, Wq, bq, Wk, bk, Wv, bv, q, kk, vv);
    k_edge<<<(N_EDGES * 8) / 256, 256, 0, stream>>>(q, kk, src, dst, dist, Wd, bd, lg, cnt);
    k_scan1<<<nscan, 1024, 0, stream>>>(cnt, loc, bsum, N_NODES);
    k_scan2<<<1, 64, 0, stream>>>(bsum, nscan);
    k_scan3<<<(N_NODES + 255) / 256, 256, 0, stream>>>(cnt, loc, bsum, rowptr, cursor, N_NODES);
    k_scatter<<<(N_EDGES + 255) / 256, 256, 0, stream>>>(src, dst, cursor, esort, dsort);
    k_node<<<N_NODES / 4, 256, 0, stream>>>(lg, vv, x, esort, dsort, rowptr, hupd, disp);
    k_hout_gate<<<N_NODES / 16, 256, 0, stream>>>(h, hupd, Wo, bo, Wg1, bg1, Wg2, bg2,
                                                  x, disp, hout, xout);
}

// Round 3
// 440.665 us; speedup vs baseline: 1.4320x; 1.0690x over previous
//
#include <hip/hip_runtime.h>
#include <math.h>

#define N_NODES 50000
#define N_EDGES 500000
#define HIDDEN 128
#define HEADS 8
#define HEAD_DIM 16

typedef __attribute__((ext_vector_type(8))) short short8;     // 8 bf16 (4 VGPRs) MFMA A/B frag
typedef __attribute__((ext_vector_type(4))) float floatx4;    // MFMA C/D frag
typedef __attribute__((ext_vector_type(4))) unsigned short ushort4v;

// workspace layout, element offsets (4-byte units)
#define OFF_Q       0u          // q fp32 [50000x128]; reused for dsort/loc/bsum after k_edge
#define OFF_K       6400000u    // k fp32; reused as h_upd after k_edge
#define OFF_V       12800000u   // v fp32
#define OFF_LG      19200000u   // lg [E x 8] AFTER k_edge; h_hi bf16 [50000x128] BEFORE (dead then)
#define OFF_DISP    23200000u
#define OFF_CNT     23350016u
#define OFF_ROWPTR  23400032u
#define OFF_CURSOR  23450048u
#define OFF_ESORT   23500064u
#define OFF_HLO     24000064u   // h_lo bf16 [50000x128] = 3.2M float slots
#define OFF_WSPLIT  27200064u   // W{q,k,v} split-bf16 in frag order: 98,304 float slots
// end: 27,298,368 floats = 109.2 MB

static __device__ __forceinline__ unsigned short f2bf(float f) {
    unsigned u = __builtin_bit_cast(unsigned, f);
    unsigned r = (u + 0x7FFFu + ((u >> 16) & 1u)) >> 16;      // RNE
    return (unsigned short)r;
}
static __device__ __forceinline__ float bf2f(unsigned short s) {
    return __builtin_bit_cast(float, (unsigned)s << 16);
}

__global__ void k_zero_int(int* __restrict__ p, int n) {
    int i = blockIdx.x * 256 + threadIdx.x;
    if (i < n) p[i] = 0;
}

// split h into hi/lo bf16, row-major (grid exact: 6.4M elems / 4 per thread)
__global__ __launch_bounds__(256) void k_split_h(
    const float* __restrict__ h,
    unsigned short* __restrict__ hhi, unsigned short* __restrict__ hlo) {
    int i = (blockIdx.x * 256 + threadIdx.x) * 4;
    float4 xv = *(const float4*)(h + i);
    ushort4v hi, lo;
    float v0[4] = {xv.x, xv.y, xv.z, xv.w};
#pragma unroll
    for (int j = 0; j < 4; ++j) {
        unsigned short a = f2bf(v0[j]);
        hi[j] = a;
        lo[j] = f2bf(v0[j] - bf2f(a));
    }
    *(ushort4v*)(hhi + i) = hi;
    *(ushort4v*)(hlo + i) = lo;
}

// repack Wq/Wk/Wv into split-bf16 MFMA B-fragment order:
// frag(m,kc,ct,hilo): 64 lanes x 8 bf16, lane holds B[k=kc*32+(lane>>4)*8+j][n=ct*16+(lane&15)]
__global__ void k_split_w(const float* __restrict__ Wq, const float* __restrict__ Wk,
                          const float* __restrict__ Wv, unsigned short* __restrict__ ws) {
    int t = blockIdx.x * 256 + threadIdx.x;          // grid exact: 3*16384
    int m = t >> 14, r = t & 16383;
    int k = r >> 7, n = r & 127;
    const float* W = (m == 0) ? Wq : (m == 1) ? Wk : Wv;
    float x = W[k * 128 + n];
    int kc = k >> 5, kin = k & 31, quad = kin >> 3, j = kin & 7;
    int ct = n >> 4, nin = n & 15, lane = quad * 16 + nin;
    unsigned base = ((((unsigned)(m * 4 + kc) * 8 + ct) * 2) * 64 + lane) * 8 + j;
    unsigned short a = f2bf(x);
    ws[base] = a;                                    // hilo=0
    ws[base + 512] = f2bf(x - bf2f(a));              // hilo=1 (+64 lanes*8)
}

// q/k/v via split-bf16 MFMA: block=256 (4 waves), 32 rows/block, wave w owns
// col-tiles {2w, 2w+1} for all 3 mats. K=128 as 4 chunks of 32.
__global__ __launch_bounds__(256) void k_qkv_mfma(
    const unsigned short* __restrict__ hhi, const unsigned short* __restrict__ hlo,
    const unsigned short* __restrict__ wsp,
    const float* __restrict__ bq, const float* __restrict__ bk, const float* __restrict__ bv,
    float* __restrict__ q, float* __restrict__ k, float* __restrict__ v) {
    const int wave = threadIdx.x >> 6, lane = threadIdx.x & 63;
    const int quad = lane >> 4, l15 = lane & 15;
    const int ct0 = wave * 2;
    const int row0 = blockIdx.x * 32;

    floatx4 acc[3][2][2];                            // [mat][ctl][rt]
#pragma unroll
    for (int m = 0; m < 3; ++m)
#pragma unroll
        for (int c = 0; c < 2; ++c)
#pragma unroll
            for (int r = 0; r < 2; ++r) acc[m][c][r] = (floatx4){0.f, 0.f, 0.f, 0.f};

#pragma unroll
    for (int kc = 0; kc < 4; ++kc) {
        short8 ah[2], al[2];
#pragma unroll
        for (int rt = 0; rt < 2; ++rt) {
            int row = row0 + rt * 16 + l15;
            if (row >= N_NODES) row = N_NODES - 1;
            size_t off = (size_t)row * 128 + kc * 32 + quad * 8;
            ah[rt] = *(const short8*)(hhi + off);
            al[rt] = *(const short8*)(hlo + off);
        }
#pragma unroll
        for (int m = 0; m < 3; ++m) {
#pragma unroll
            for (int ctl = 0; ctl < 2; ++ctl) {
                unsigned fb = ((((unsigned)(m * 4 + kc) * 8 + (ct0 + ctl)) * 2) * 64 + lane) * 8;
                short8 bh = *(const short8*)(wsp + fb);
                short8 bl = *(const short8*)(wsp + fb + 512);
#pragma unroll
                for (int rt = 0; rt < 2; ++rt) {
                    acc[m][ctl][rt] = __builtin_amdgcn_mfma_f32_16x16x32_bf16(
                        ah[rt], bh, acc[m][ctl][rt], 0, 0, 0);
                    acc[m][ctl][rt] = __builtin_amdgcn_mfma_f32_16x16x32_bf16(
                        ah[rt], bl, acc[m][ctl][rt], 0, 0, 0);
                    acc[m][ctl][rt] = __builtin_amdgcn_mfma_f32_16x16x32_bf16(
                        al[rt], bh, acc[m][ctl][rt], 0, 0, 0);
                }
            }
        }
    }

    float* outs[3] = {q, k, v};
    const float* biases[3] = {bq, bk, bv};
#pragma unroll
    for (int m = 0; m < 3; ++m) {
#pragma unroll
        for (int ctl = 0; ctl < 2; ++ctl) {
            int col = (ct0 + ctl) * 16 + l15;
            float bias = biases[m][col];
#pragma unroll
            for (int rt = 0; rt < 2; ++rt) {
#pragma unroll
                for (int reg = 0; reg < 4; ++reg) {
                    int row = row0 + rt * 16 + quad * 4 + reg;
                    if (row < N_NODES)
                        outs[m][(size_t)row * 128 + col] = acc[m][ctl][rt][reg] + bias;
                }
            }
        }
    }
}

// one thread per (edge, head): lg = q[src].k[dst]/4 - (d^2*Wd + bd); fused degree count
__global__ __launch_bounds__(256) void k_edge(
    const float* __restrict__ q, const float* __restrict__ k,
    const int* __restrict__ src, const int* __restrict__ dst,
    const float* __restrict__ dist,
    const float* __restrict__ Wd, const float* __restrict__ bd,
    float* __restrict__ lg, int* __restrict__ cnt) {
    int t = blockIdx.x * 256 + threadIdx.x;   // grid exact: E*8 threads
    int e = t >> 3, hd = t & 7;
    int s = src[e], d = dst[e];
    const float4* qp = (const float4*)(q + (size_t)s * HIDDEN + hd * HEAD_DIM);
    const float4* kp = (const float4*)(k + (size_t)d * HIDDEN + hd * HEAD_DIM);
    float dot = 0.f;
#pragma unroll
    for (int j = 0; j < 4; ++j) {
        float4 a = qp[j], b = kp[j];
        dot += a.x * b.x + a.y * b.y + a.z * b.z + a.w * b.w;
    }
    float dd = dist[e];
    lg[(size_t)e * 8 + hd] = dot * 0.25f - (dd * dd * Wd[hd] + bd[hd]);
    if (hd == 0) atomicAdd(&cnt[s], 1);
}

// hierarchical scan over 50000 counts
__global__ __launch_bounds__(1024) void k_scan1(const int* __restrict__ cnt,
                                                int* __restrict__ loc,
                                                int* __restrict__ bsum, int n) {
    __shared__ int buf[1024];
    int t = threadIdx.x;
    int i = blockIdx.x * 1024 + t;
    int val = (i < n) ? cnt[i] : 0;
    buf[t] = val;
    __syncthreads();
    for (int off = 1; off < 1024; off <<= 1) {
        int a = (t >= off) ? buf[t - off] : 0;
        __syncthreads();
        buf[t] += a;
        __syncthreads();
    }
    if (i < n) loc[i] = buf[t];
    if (t == 1023) bsum[blockIdx.x] = buf[1023];
}

__global__ void k_scan2(int* __restrict__ bsum, int nb) {
    int t = threadIdx.x;
    int v = (t < nb) ? bsum[t] : 0;
    for (int off = 1; off < 64; off <<= 1) {
        int a = __shfl_up(v, off);
        if (t >= off) v += a;
    }
    if (t < nb) bsum[t] = v;
}

__global__ void k_scan3(const int* __restrict__ cnt, const int* __restrict__ loc,
                        const int* __restrict__ bsum,
                        int* __restrict__ rowptr, int* __restrict__ cursor, int n) {
    int i = blockIdx.x * 256 + threadIdx.x;
    if (i < n) {
        int off = (i >= 1024) ? bsum[(i >> 10) - 1] : 0;
        int incl = loc[i] + off;
        rowptr[i + 1] = incl;
        cursor[i] = incl - cnt[i];
    }
    if (i == 0) rowptr[0] = 0;
}

__global__ void k_scatter(const int* __restrict__ src, const int* __restrict__ dst,
                          int* __restrict__ cursor,
                          int* __restrict__ esort, int* __restrict__ dsort) {
    int e = blockIdx.x * 256 + threadIdx.x;
    if (e < N_EDGES) {
        int pos = atomicAdd(&cursor[src[e]], 1);
        esort[pos] = e;
        dsort[pos] = dst[e];
    }
}

// one wave per node: softmax stats + weighted v-gather accumulation
__global__ __launch_bounds__(256) void k_node(
    const float* __restrict__ lg, const float* __restrict__ v,
    const float* __restrict__ x,
    const int* __restrict__ esort, const int* __restrict__ dsort,
    const int* __restrict__ rowptr,
    float* __restrict__ hupd, float* __restrict__ disp) {
    __shared__ float wbuf_all[4][512];
    const int wave = threadIdx.x >> 6, lane = threadIdx.x & 63;
    float* wbuf = wbuf_all[wave];
    const int node = blockIdx.x * 4 + wave;
    const int beg = rowptr[node], end = rowptr[node + 1];

    float m[8];
#pragma unroll
    for (int j = 0; j < 8; ++j) m[j] = -3.0e38f;
    for (int cb = beg; cb < end; cb += 64) {
        int idx = cb + lane;
        if (idx < end) {
            int e = esort[idx];
            const float4* lp = (const float4*)(lg + (size_t)e * 8);
            float4 a = lp[0], b = lp[1];
            m[0] = fmaxf(m[0], a.x); m[1] = fmaxf(m[1], a.y);
            m[2] = fmaxf(m[2], a.z); m[3] = fmaxf(m[3], a.w);
            m[4] = fmaxf(m[4], b.x); m[5] = fmaxf(m[5], b.y);
            m[6] = fmaxf(m[6], b.z); m[7] = fmaxf(m[7], b.w);
        }
    }
    for (int off = 1; off < 64; off <<= 1) {
#pragma unroll
        for (int j = 0; j < 8; ++j) m[j] = fmaxf(m[j], __shfl_xor(m[j], off));
    }

    float s[8];
#pragma unroll
    for (int j = 0; j < 8; ++j) s[j] = 0.f;
    const int hp  = lane >> 3;
    const int hq  = lane & 7;
    const int dim = lane >> 3;
    float xs = 0.f;
    if (lane < 24) xs = x[node * 3 + dim];
    float acc0 = 0.f, acc1 = 0.f, da = 0.f;

    for (int cb = beg; cb < end; cb += 64) {
        int idx = cb + lane;
        int clen = min(64, end - cb);
        int d = 0;
        if (idx < end) {
            int e = esort[idx];
            d = dsort[idx];
            const float4* lp = (const float4*)(lg + (size_t)e * 8);
            float4 a = lp[0], b = lp[1];
            float wv[8];
            wv[0] = __expf(a.x - m[0]); wv[1] = __expf(a.y - m[1]);
            wv[2] = __expf(a.z - m[2]); wv[3] = __expf(a.w - m[3]);
            wv[4] = __expf(b.x - m[4]); wv[5] = __expf(b.y - m[5]);
            wv[6] = __expf(b.z - m[6]); wv[7] = __expf(b.w - m[7]);
#pragma unroll
            for (int j = 0; j < 8; ++j) {
                s[j] += wv[j];
                wbuf[j * 64 + lane] = wv[j];
            }
        }
        __asm__ volatile("s_waitcnt lgkmcnt(0)" ::: "memory");
        for (int i = 0; i < clen; ++i) {
            int di = __shfl(d, i);
            float wa = wbuf[hp * 64 + i];
            const float2 vv = *(const float2*)(v + (size_t)di * HIDDEN + 2 * lane);
            acc0 += vv.x * wa;
            acc1 += vv.y * wa;
            if (lane < 24) {
                float wd = wbuf[hq * 64 + i];
                da += (x[di * 3 + dim] - xs) * wd;
            }
        }
        __asm__ volatile("" ::: "memory");
    }

    for (int off = 1; off < 64; off <<= 1) {
#pragma unroll
        for (int j = 0; j < 8; ++j) s[j] += __shfl_xor(s[j], off);
    }
    float inva = 1.f / fmaxf(s[hp], 1e-9f);
    float2 o; o.x = acc0 * inva; o.y = acc1 * inva;
    *(float2*)(hupd + (size_t)node * HIDDEN + 2 * lane) = o;
    if (lane < 24) da *= 0.125f / fmaxf(s[hq], 1e-9f);
    da += __shfl_xor(da, 1);
    da += __shfl_xor(da, 2);
    da += __shfl_xor(da, 4);
    if (lane < 24 && hq == 0) disp[node * 3 + dim] = da;
}

// fused epilogue: hout = h + hupd@Wo + bo; t1=silu(hout@Wg1+bg1) in LDS;
// gate=tanh(t1.Wg2+bg2); xout = x + gate*disp
__global__ __launch_bounds__(256) void k_hout_gate(
    const float* __restrict__ h, const float* __restrict__ hupd,
    const float* __restrict__ Wo, const float* __restrict__ bo,
    const float* __restrict__ Wg1, const float* __restrict__ bg1,
    const float* __restrict__ Wg2, const float* __restrict__ bg2,
    const float* __restrict__ x, const float* __restrict__ disp,
    float* __restrict__ hout, float* __restrict__ xout) {
    __shared__ float hb[16 * 128];
    __shared__ float red[4][8];
    const int col  = threadIdx.x & 127;
    const int rgrp = __builtin_amdgcn_readfirstlane(threadIdx.x >> 7);
    const int row0 = blockIdx.x * 16 + rgrp * 8;

    float acc[8] = {0};
    for (int k0 = 0; k0 < HIDDEN; k0 += 4) {
        float w[4];
#pragma unroll
        for (int j = 0; j < 4; ++j) w[j] = Wo[(k0 + j) * HIDDEN + col];
#pragma unroll
        for (int r = 0; r < 8; ++r) {
            const float* hp = hupd + (size_t)(row0 + r) * HIDDEN + k0;
            acc[r] += hp[0] * w[0] + hp[1] * w[1] + hp[2] * w[2] + hp[3] * w[3];
        }
    }
    const float bo_ = bo[col];
#pragma unroll
    for (int r = 0; r < 8; ++r) {
        size_t oo = (size_t)(row0 + r) * HIDDEN + col;
        float val = h[oo] + acc[r] + bo_;
        hout[oo] = val;
        hb[(rgrp * 8 + r) * 128 + col] = val;
    }
    __syncthreads();

    float acc2[8] = {0};
    for (int k0 = 0; k0 < HIDDEN; k0 += 4) {
        float w[4];
#pragma unroll
        for (int j = 0; j < 4; ++j) w[j] = Wg1[(k0 + j) * HIDDEN + col];
#pragma unroll
        for (int r = 0; r < 8; ++r) {
            const float* hp = hb + (rgrp * 8 + r) * 128 + k0;
            acc2[r] += hp[0] * w[0] + hp[1] * w[1] + hp[2] * w[2] + hp[3] * w[3];
        }
    }
    const float bg1_ = bg1[col];
    const float w2 = Wg2[col];
    float p[8];
#pragma unroll
    for (int r = 0; r < 8; ++r) {
        float z = acc2[r] + bg1_;
        p[r] = (z / (1.f + __expf(-z))) * w2;
    }
    for (int off = 1; off < 64; off <<= 1) {
#pragma unroll
        for (int r = 0; r < 8; ++r) p[r] += __shfl_xor(p[r], off);
    }
    const int wavei = threadIdx.x >> 6, lane = threadIdx.x & 63;
    if (lane == 0) {
#pragma unroll
        for (int r = 0; r < 8; ++r) red[wavei][r] = p[r];
    }
    __syncthreads();
    int t = threadIdx.x;
    if (t < 16) {
        int rg = t >> 3, r = t & 7;
        float sum = red[rg * 2][r] + red[rg * 2 + 1][r];
        float g = tanhf(sum + bg2[0]);
        int row = blockIdx.x * 16 + t;
#pragma unroll
        for (int dd = 0; dd < 3; ++dd) {
            int oo = row * 3 + dd;
            xout[oo] = x[oo] + g * disp[oo];
        }
    }
}

extern "C" void kernel_launch(void* const* d_in, const int* in_sizes, int n_in,
                              void* d_out, int out_size, void* d_ws, size_t ws_size,
                              hipStream_t stream) {
    const float* h    = (const float*)d_in[0];
    const float* x    = (const float*)d_in[1];
    const int*   src  = (const int*)d_in[2];
    const int*   dst  = (const int*)d_in[3];
    const float* dist = (const float*)d_in[4];
    const float* Wq = (const float*)d_in[5];  const float* bq = (const float*)d_in[6];
    const float* Wk = (const float*)d_in[7];  const float* bk = (const float*)d_in[8];
    const float* Wv = (const float*)d_in[9];  const float* bv = (const float*)d_in[10];
    const float* Wo = (const float*)d_in[11]; const float* bo = (const float*)d_in[12];
    const float* Wd = (const float*)d_in[13]; const float* bd = (const float*)d_in[14];
    const float* Wg1 = (const float*)d_in[15]; const float* bg1 = (const float*)d_in[16];
    const float* Wg2 = (const float*)d_in[17]; const float* bg2 = (const float*)d_in[18];

    float* ws   = (float*)d_ws;
    float* q    = ws + OFF_Q;
    float* kk   = ws + OFF_K;
    float* vv   = ws + OFF_V;
    float* lg   = ws + OFF_LG;
    float* disp = ws + OFF_DISP;
    int* cnt    = (int*)(ws + OFF_CNT);
    int* rowptr = (int*)(ws + OFF_ROWPTR);
    int* cursor = (int*)(ws + OFF_CURSOR);
    int* esort  = (int*)(ws + OFF_ESORT);
    unsigned short* hhi = (unsigned short*)(ws + OFF_LG);   // dead before k_edge writes lg
    unsigned short* hlo = (unsigned short*)(ws + OFF_HLO);
    unsigned short* wsp = (unsigned short*)(ws + OFF_WSPLIT);
    int* dsort  = (int*)(ws + OFF_Q);             // q dead after k_edge
    int* loc    = (int*)(ws + OFF_Q + 500000u);
    int* bsum   = (int*)(ws + OFF_Q + 550000u);
    float* hupd = kk;                             // k dead after k_edge
    float* hout = (float*)d_out;
    float* xout = hout + (size_t)N_NODES * HIDDEN;

    const int nscan = (N_NODES + 1023) / 1024;    // 49

    k_split_h<<<6250, 256, 0, stream>>>(h, hhi, hlo);
    k_split_w<<<192, 256, 0, stream>>>(Wq, Wk, Wv, wsp);
    k_zero_int<<<(N_NODES + 255) / 256, 256, 0, stream>>>(cnt, N_NODES);
    k_qkv_mfma<<<(N_NODES + 31) / 32, 256, 0, stream>>>(hhi, hlo, wsp, bq, bk, bv, q, kk, vv);
    k_edge<<<(N_EDGES * 8) / 256, 256, 0, stream>>>(q, kk, src, dst, dist, Wd, bd, lg, cnt);
    k_scan1<<<nscan, 1024, 0, stream>>>(cnt, loc, bsum, N_NODES);
    k_scan2<<<1, 64, 0, stream>>>(bsum, nscan);
    k_scan3<<<(N_NODES + 255) / 256, 256, 0, stream>>>(cnt, loc, bsum, rowptr, cursor, N_NODES);
    k_scatter<<<(N_EDGES + 255) / 256, 256, 0, stream>>>(src, dst, cursor, esort, dsort);
    k_node<<<N_NODES / 4, 256, 0, stream>>>(lg, vv, x, esort, dsort, rowptr, hupd, disp);
    k_hout_gate<<<N_NODES / 16, 256, 0, stream>>>(h, hupd, Wo, bo, Wg1, bg1, Wg2, bg2,
                                                  x, disp, hout, xout);
}

// Round 4
// 386.702 us; speedup vs baseline: 1.6318x; 1.1395x over previous
//
#include <hip/hip_runtime.h>
#include <math.h>

#define N_NODES 50000
#define N_EDGES 500000
#define HIDDEN 128
#define HEADS 8
#define HEAD_DIM 16

typedef __attribute__((ext_vector_type(8))) short short8;     // 8 bf16 (4 VGPRs) MFMA A/B frag
typedef __attribute__((ext_vector_type(4))) float floatx4;    // MFMA C/D frag
typedef __attribute__((ext_vector_type(4))) unsigned short ushort4v;

// workspace layout, element offsets (4-byte units)
#define OFF_Q       0u          // q fp32 [50000x128]; reused for dsort/loc/bsum after k_edge
#define OFF_K       6400000u    // k fp32; reused as hupd_hi/lo bf16 after k_edge
#define OFF_V       12800000u   // v fp32
#define OFF_LG      19200000u   // lg [E x 8] AFTER k_edge; h_hi bf16 BEFORE (dead then)
#define OFF_DISP    23200000u
#define OFF_CNT     23350016u
#define OFF_ROWPTR  23400032u
#define OFF_CURSOR  23450048u
#define OFF_ESORT   23500064u
#define OFF_HLO     24000064u   // h_lo bf16 [50000x128] = 3.2M float slots
#define OFF_WSPLIT  27200064u   // W{q,k,v,o,g1} split-bf16 frag order: 81,920 float slots
// end: 27,281,984 floats = 109.1 MB

static __device__ __forceinline__ unsigned short f2bf(float f) {
    unsigned u = __builtin_bit_cast(unsigned, f);
    unsigned r = (u + 0x7FFFu + ((u >> 16) & 1u)) >> 16;      // RNE
    return (unsigned short)r;
}
static __device__ __forceinline__ float bf2f(unsigned short s) {
    return __builtin_bit_cast(float, (unsigned)s << 16);
}

__global__ void k_zero_int(int* __restrict__ p, int n) {
    int i = blockIdx.x * 256 + threadIdx.x;
    if (i < n) p[i] = 0;
}

// split h into hi/lo bf16, row-major (grid exact: 6.4M elems / 4 per thread)
__global__ __launch_bounds__(256) void k_split_h(
    const float* __restrict__ h,
    unsigned short* __restrict__ hhi, unsigned short* __restrict__ hlo) {
    int i = (blockIdx.x * 256 + threadIdx.x) * 4;
    float4 xv = *(const float4*)(h + i);
    ushort4v hi, lo;
    float v0[4] = {xv.x, xv.y, xv.z, xv.w};
#pragma unroll
    for (int j = 0; j < 4; ++j) {
        unsigned short a = f2bf(v0[j]);
        hi[j] = a;
        lo[j] = f2bf(v0[j] - bf2f(a));
    }
    *(ushort4v*)(hhi + i) = hi;
    *(ushort4v*)(hlo + i) = lo;
}

// repack W{q,k,v,o,g1} into split-bf16 MFMA B-fragment order:
// frag(m,kc,ct,hilo): 64 lanes x 8 bf16, lane holds B[k=kc*32+(lane>>4)*8+j][n=ct*16+(lane&15)]
__global__ void k_split_w(const float* __restrict__ Wq, const float* __restrict__ Wk,
                          const float* __restrict__ Wv, const float* __restrict__ Wo,
                          const float* __restrict__ Wg1, unsigned short* __restrict__ ws) {
    int t = blockIdx.x * 256 + threadIdx.x;          // grid exact: 5*16384
    int m = t >> 14, r = t & 16383;
    int k = r >> 7, n = r & 127;
    const float* W = (m == 0) ? Wq : (m == 1) ? Wk : (m == 2) ? Wv : (m == 3) ? Wo : Wg1;
    float x = W[k * 128 + n];
    int kc = k >> 5, kin = k & 31, quad = kin >> 3, j = kin & 7;
    int ct = n >> 4, nin = n & 15, lane = quad * 16 + nin;
    unsigned base = ((((unsigned)(m * 4 + kc) * 8 + ct) * 2) * 64 + lane) * 8 + j;
    unsigned short a = f2bf(x);
    ws[base] = a;                                    // hilo=0
    ws[base + 512] = f2bf(x - bf2f(a));              // hilo=1 (+64 lanes*8)
}

// q/k/v via split-bf16 MFMA: block=256 (4 waves), 32 rows/block, wave w owns
// col-tiles {2w, 2w+1} for all 3 mats. K=128 as 4 chunks of 32.
__global__ __launch_bounds__(256) void k_qkv_mfma(
    const unsigned short* __restrict__ hhi, const unsigned short* __restrict__ hlo,
    const unsigned short* __restrict__ wsp,
    const float* __restrict__ bq, const float* __restrict__ bk, const float* __restrict__ bv,
    float* __restrict__ q, float* __restrict__ k, float* __restrict__ v) {
    const int wave = threadIdx.x >> 6, lane = threadIdx.x & 63;
    const int quad = lane >> 4, l15 = lane & 15;
    const int ct0 = wave * 2;
    const int row0 = blockIdx.x * 32;

    floatx4 acc[3][2][2];                            // [mat][ctl][rt]
#pragma unroll
    for (int m = 0; m < 3; ++m)
#pragma unroll
        for (int c = 0; c < 2; ++c)
#pragma unroll
            for (int r = 0; r < 2; ++r) acc[m][c][r] = (floatx4){0.f, 0.f, 0.f, 0.f};

#pragma unroll
    for (int kc = 0; kc < 4; ++kc) {
        short8 ah[2], al[2];
#pragma unroll
        for (int rt = 0; rt < 2; ++rt) {
            int row = row0 + rt * 16 + l15;
            if (row >= N_NODES) row = N_NODES - 1;
            size_t off = (size_t)row * 128 + kc * 32 + quad * 8;
            ah[rt] = *(const short8*)(hhi + off);
            al[rt] = *(const short8*)(hlo + off);
        }
#pragma unroll
        for (int m = 0; m < 3; ++m) {
#pragma unroll
            for (int ctl = 0; ctl < 2; ++ctl) {
                unsigned fb = ((((unsigned)(m * 4 + kc) * 8 + (ct0 + ctl)) * 2) * 64 + lane) * 8;
                short8 bh = *(const short8*)(wsp + fb);
                short8 bl = *(const short8*)(wsp + fb + 512);
#pragma unroll
                for (int rt = 0; rt < 2; ++rt) {
                    acc[m][ctl][rt] = __builtin_amdgcn_mfma_f32_16x16x32_bf16(
                        ah[rt], bh, acc[m][ctl][rt], 0, 0, 0);
                    acc[m][ctl][rt] = __builtin_amdgcn_mfma_f32_16x16x32_bf16(
                        ah[rt], bl, acc[m][ctl][rt], 0, 0, 0);
                    acc[m][ctl][rt] = __builtin_amdgcn_mfma_f32_16x16x32_bf16(
                        al[rt], bh, acc[m][ctl][rt], 0, 0, 0);
                }
            }
        }
    }

    float* outs[3] = {q, k, v};
    const float* biases[3] = {bq, bk, bv};
#pragma unroll
    for (int m = 0; m < 3; ++m) {
#pragma unroll
        for (int ctl = 0; ctl < 2; ++ctl) {
            int col = (ct0 + ctl) * 16 + l15;
            float bias = biases[m][col];
#pragma unroll
            for (int rt = 0; rt < 2; ++rt) {
#pragma unroll
                for (int reg = 0; reg < 4; ++reg) {
                    int row = row0 + rt * 16 + quad * 4 + reg;
                    if (row < N_NODES)
                        outs[m][(size_t)row * 128 + col] = acc[m][ctl][rt][reg] + bias;
                }
            }
        }
    }
}

// one thread per (edge, head): lg = q[src].k[dst]/4 - (d^2*Wd + bd); fused degree count
__global__ __launch_bounds__(256) void k_edge(
    const float* __restrict__ q, const float* __restrict__ k,
    const int* __restrict__ src, const int* __restrict__ dst,
    const float* __restrict__ dist,
    const float* __restrict__ Wd, const float* __restrict__ bd,
    float* __restrict__ lg, int* __restrict__ cnt) {
    int t = blockIdx.x * 256 + threadIdx.x;   // grid exact: E*8 threads
    int e = t >> 3, hd = t & 7;
    int s = src[e], d = dst[e];
    const float4* qp = (const float4*)(q + (size_t)s * HIDDEN + hd * HEAD_DIM);
    const float4* kp = (const float4*)(k + (size_t)d * HIDDEN + hd * HEAD_DIM);
    float dot = 0.f;
#pragma unroll
    for (int j = 0; j < 4; ++j) {
        float4 a = qp[j], b = kp[j];
        dot += a.x * b.x + a.y * b.y + a.z * b.z + a.w * b.w;
    }
    float dd = dist[e];
    lg[(size_t)e * 8 + hd] = dot * 0.25f - (dd * dd * Wd[hd] + bd[hd]);
    if (hd == 0) atomicAdd(&cnt[s], 1);
}

// hierarchical scan over 50000 counts
__global__ __launch_bounds__(1024) void k_scan1(const int* __restrict__ cnt,
                                                int* __restrict__ loc,
                                                int* __restrict__ bsum, int n) {
    __shared__ int buf[1024];
    int t = threadIdx.x;
    int i = blockIdx.x * 1024 + t;
    int val = (i < n) ? cnt[i] : 0;
    buf[t] = val;
    __syncthreads();
    for (int off = 1; off < 1024; off <<= 1) {
        int a = (t >= off) ? buf[t - off] : 0;
        __syncthreads();
        buf[t] += a;
        __syncthreads();
    }
    if (i < n) loc[i] = buf[t];
    if (t == 1023) bsum[blockIdx.x] = buf[1023];
}

__global__ void k_scan2(int* __restrict__ bsum, int nb) {
    int t = threadIdx.x;
    int v = (t < nb) ? bsum[t] : 0;
    for (int off = 1; off < 64; off <<= 1) {
        int a = __shfl_up(v, off);
        if (t >= off) v += a;
    }
    if (t < nb) bsum[t] = v;
}

__global__ void k_scan3(const int* __restrict__ cnt, const int* __restrict__ loc,
                        const int* __restrict__ bsum,
                        int* __restrict__ rowptr, int* __restrict__ cursor, int n) {
    int i = blockIdx.x * 256 + threadIdx.x;
    if (i < n) {
        int off = (i >= 1024) ? bsum[(i >> 10) - 1] : 0;
        int incl = loc[i] + off;
        rowptr[i + 1] = incl;
        cursor[i] = incl - cnt[i];
    }
    if (i == 0) rowptr[0] = 0;
}

__global__ void k_scatter(const int* __restrict__ src, const int* __restrict__ dst,
                          int* __restrict__ cursor,
                          int* __restrict__ esort, int* __restrict__ dsort) {
    int e = blockIdx.x * 256 + threadIdx.x;
    if (e < N_EDGES) {
        int pos = atomicAdd(&cursor[src[e]], 1);
        esort[pos] = e;
        dsort[pos] = dst[e];
    }
}

// one wave per node: softmax stats + weighted v-gather accumulation.
// hupd written as split-bf16 hi/lo (consumed by MFMA epilogue).
__global__ __launch_bounds__(256) void k_node(
    const float* __restrict__ lg, const float* __restrict__ v,
    const float* __restrict__ x,
    const int* __restrict__ esort, const int* __restrict__ dsort,
    const int* __restrict__ rowptr,
    unsigned short* __restrict__ hupd_hi, unsigned short* __restrict__ hupd_lo,
    float* __restrict__ disp) {
    __shared__ float wbuf_all[4][512];
    const int wave = threadIdx.x >> 6, lane = threadIdx.x & 63;
    float* wbuf = wbuf_all[wave];
    const int node = blockIdx.x * 4 + wave;
    const int beg = rowptr[node], end = rowptr[node + 1];

    float m[8];
#pragma unroll
    for (int j = 0; j < 8; ++j) m[j] = -3.0e38f;
    for (int cb = beg; cb < end; cb += 64) {
        int idx = cb + lane;
        if (idx < end) {
            int e = esort[idx];
            const float4* lp = (const float4*)(lg + (size_t)e * 8);
            float4 a = lp[0], b = lp[1];
            m[0] = fmaxf(m[0], a.x); m[1] = fmaxf(m[1], a.y);
            m[2] = fmaxf(m[2], a.z); m[3] = fmaxf(m[3], a.w);
            m[4] = fmaxf(m[4], b.x); m[5] = fmaxf(m[5], b.y);
            m[6] = fmaxf(m[6], b.z); m[7] = fmaxf(m[7], b.w);
        }
    }
    for (int off = 1; off < 64; off <<= 1) {
#pragma unroll
        for (int j = 0; j < 8; ++j) m[j] = fmaxf(m[j], __shfl_xor(m[j], off));
    }

    float s[8];
#pragma unroll
    for (int j = 0; j < 8; ++j) s[j] = 0.f;
    const int hp  = lane >> 3;
    const int hq  = lane & 7;
    const int dim = lane >> 3;
    float xs = 0.f;
    if (lane < 24) xs = x[node * 3 + dim];
    float acc0 = 0.f, acc1 = 0.f, da = 0.f;

    for (int cb = beg; cb < end; cb += 64) {
        int idx = cb + lane;
        int clen = min(64, end - cb);
        int d = 0;
        if (idx < end) {
            int e = esort[idx];
            d = dsort[idx];
            const float4* lp = (const float4*)(lg + (size_t)e * 8);
            float4 a = lp[0], b = lp[1];
            float wv[8];
            wv[0] = __expf(a.x - m[0]); wv[1] = __expf(a.y - m[1]);
            wv[2] = __expf(a.z - m[2]); wv[3] = __expf(a.w - m[3]);
            wv[4] = __expf(b.x - m[4]); wv[5] = __expf(b.y - m[5]);
            wv[6] = __expf(b.z - m[6]); wv[7] = __expf(b.w - m[7]);
#pragma unroll
            for (int j = 0; j < 8; ++j) {
                s[j] += wv[j];
                wbuf[j * 64 + lane] = wv[j];
            }
        }
        __asm__ volatile("s_waitcnt lgkmcnt(0)" ::: "memory");
        for (int i = 0; i < clen; ++i) {
            int di = __shfl(d, i);
            float wa = wbuf[hp * 64 + i];
            const float2 vv = *(const float2*)(v + (size_t)di * HIDDEN + 2 * lane);
            acc0 += vv.x * wa;
            acc1 += vv.y * wa;
            if (lane < 24) {
                float wd = wbuf[hq * 64 + i];
                da += (x[di * 3 + dim] - xs) * wd;
            }
        }
        __asm__ volatile("" ::: "memory");
    }

    for (int off = 1; off < 64; off <<= 1) {
#pragma unroll
        for (int j = 0; j < 8; ++j) s[j] += __shfl_xor(s[j], off);
    }
    float inva = 1.f / fmaxf(s[hp], 1e-9f);
    float o0 = acc0 * inva, o1 = acc1 * inva;
    unsigned short h0 = f2bf(o0), h1 = f2bf(o1);
    unsigned short l0 = f2bf(o0 - bf2f(h0)), l1 = f2bf(o1 - bf2f(h1));
    ((unsigned*)hupd_hi)[(size_t)node * 64 + lane] = (unsigned)h0 | ((unsigned)h1 << 16);
    ((unsigned*)hupd_lo)[(size_t)node * 64 + lane] = (unsigned)l0 | ((unsigned)l1 << 16);
    if (lane < 24) da *= 0.125f / fmaxf(s[hq], 1e-9f);
    da += __shfl_xor(da, 1);
    da += __shfl_xor(da, 2);
    da += __shfl_xor(da, 4);
    if (lane < 24 && hq == 0) disp[node * 3 + dim] = da;
}

// fused MFMA epilogue: hout = h + hupd@Wo + bo (GEMM1, split-bf16 MFMA);
// hout staged in per-wave padded LDS (C->A layout transpose);
// GEMM2 = hout@Wg1; gate = tanh(sum_col silu(.)*Wg2); xout = x + gate*disp.
// One wave per 16 rows, 4 waves/block = 64 rows/block.
__global__ __launch_bounds__(256) void k_hout_gate(
    const float* __restrict__ h,
    const unsigned short* __restrict__ hupd_hi, const unsigned short* __restrict__ hupd_lo,
    const unsigned short* __restrict__ wsp,
    const float* __restrict__ bo, const float* __restrict__ bg1,
    const float* __restrict__ Wg2, const float* __restrict__ bg2,
    const float* __restrict__ x, const float* __restrict__ disp,
    float* __restrict__ hout, float* __restrict__ xout) {
    __shared__ float hb[4][16 * 132];                 // +4 dword pad per row: 2-way banks only
    const int wave = threadIdx.x >> 6, lane = threadIdx.x & 63;
    const int quad = lane >> 4, l15 = lane & 15;
    const int row0 = blockIdx.x * 64 + wave * 16;
    float* hbw = hb[wave];

    // ---- GEMM1: hupd @ Wo (m=3) ----
    floatx4 acc[8];
#pragma unroll
    for (int c = 0; c < 8; ++c) acc[c] = (floatx4){0.f, 0.f, 0.f, 0.f};
#pragma unroll
    for (int kc = 0; kc < 4; ++kc) {
        int row = row0 + l15;
        if (row >= N_NODES) row = N_NODES - 1;
        size_t aoff = (size_t)row * 128 + kc * 32 + quad * 8;
        short8 ah = *(const short8*)(hupd_hi + aoff);
        short8 al = *(const short8*)(hupd_lo + aoff);
#pragma unroll
        for (int ct = 0; ct < 8; ++ct) {
            unsigned fb = ((((unsigned)(3 * 4 + kc) * 8 + ct) * 2) * 64 + lane) * 8;
            short8 bh = *(const short8*)(wsp + fb);
            short8 bl = *(const short8*)(wsp + fb + 512);
            acc[ct] = __builtin_amdgcn_mfma_f32_16x16x32_bf16(ah, bh, acc[ct], 0, 0, 0);
            acc[ct] = __builtin_amdgcn_mfma_f32_16x16x32_bf16(ah, bl, acc[ct], 0, 0, 0);
            acc[ct] = __builtin_amdgcn_mfma_f32_16x16x32_bf16(al, bh, acc[ct], 0, 0, 0);
        }
    }

    // epilogue 1: add h + bo, write hout (global) + LDS tile
#pragma unroll
    for (int ct = 0; ct < 8; ++ct) {
        int col = ct * 16 + l15;
        float bias = bo[col];
#pragma unroll
        for (int reg = 0; reg < 4; ++reg) {
            int row = row0 + quad * 4 + reg;
            float val = acc[ct][reg] + bias;
            if (row < N_NODES) {
                val += h[(size_t)row * 128 + col];
                hout[(size_t)row * 128 + col] = val;
            }
            hbw[(quad * 4 + reg) * 132 + col] = val;
        }
    }
    // same-wave LDS producer->consumer
    __asm__ volatile("s_waitcnt lgkmcnt(0)" ::: "memory");

    // ---- GEMM2: hout @ Wg1 (m=4), A-frags read from LDS ----
    floatx4 acc2[8];
#pragma unroll
    for (int c = 0; c < 8; ++c) acc2[c] = (floatx4){0.f, 0.f, 0.f, 0.f};
#pragma unroll
    for (int kc = 0; kc < 4; ++kc) {
        const float* ap = hbw + l15 * 132 + kc * 32 + quad * 8;
        float4 f0 = *(const float4*)(ap);
        float4 f1 = *(const float4*)(ap + 4);
        float fv[8] = {f0.x, f0.y, f0.z, f0.w, f1.x, f1.y, f1.z, f1.w};
        short8 ah, al;
#pragma unroll
        for (int j = 0; j < 8; ++j) {
            unsigned short hi = f2bf(fv[j]);
            ah[j] = (short)hi;
            al[j] = (short)f2bf(fv[j] - bf2f(hi));
        }
#pragma unroll
        for (int ct = 0; ct < 8; ++ct) {
            unsigned fb = ((((unsigned)(4 * 4 + kc) * 8 + ct) * 2) * 64 + lane) * 8;
            short8 bh = *(const short8*)(wsp + fb);
            short8 bl = *(const short8*)(wsp + fb + 512);
            acc2[ct] = __builtin_amdgcn_mfma_f32_16x16x32_bf16(ah, bh, acc2[ct], 0, 0, 0);
            acc2[ct] = __builtin_amdgcn_mfma_f32_16x16x32_bf16(ah, bl, acc2[ct], 0, 0, 0);
            acc2[ct] = __builtin_amdgcn_mfma_f32_16x16x32_bf16(al, bh, acc2[ct], 0, 0, 0);
        }
    }

    // epilogue 2: silu * Wg2, reduce cols -> gate -> xout
    float pr[4] = {0.f, 0.f, 0.f, 0.f};
#pragma unroll
    for (int ct = 0; ct < 8; ++ct) {
        int col = ct * 16 + l15;
        float b1 = bg1[col];
        float w2 = Wg2[col];
#pragma unroll
        for (int reg = 0; reg < 4; ++reg) {
            float z = acc2[ct][reg] + b1;
            pr[reg] += (z / (1.f + __expf(-z))) * w2;
        }
    }
#pragma unroll
    for (int off = 1; off < 16; off <<= 1) {
#pragma unroll
        for (int reg = 0; reg < 4; ++reg) pr[reg] += __shfl_xor(pr[reg], off);
    }
    if (l15 == 0) {
        float b2 = bg2[0];
#pragma unroll
        for (int reg = 0; reg < 4; ++reg) {
            int row = row0 + quad * 4 + reg;
            if (row < N_NODES) {
                float g = tanhf(pr[reg] + b2);
#pragma unroll
                for (int dd = 0; dd < 3; ++dd) {
                    int oo = row * 3 + dd;
                    xout[oo] = x[oo] + g * disp[oo];
                }
            }
        }
    }
}

extern "C" void kernel_launch(void* const* d_in, const int* in_sizes, int n_in,
                              void* d_out, int out_size, void* d_ws, size_t ws_size,
                              hipStream_t stream) {
    const float* h    = (const float*)d_in[0];
    const float* x    = (const float*)d_in[1];
    const int*   src  = (const int*)d_in[2];
    const int*   dst  = (const int*)d_in[3];
    const float* dist = (const float*)d_in[4];
    const float* Wq = (const float*)d_in[5];  const float* bq = (const float*)d_in[6];
    const float* Wk = (const float*)d_in[7];  const float* bk = (const float*)d_in[8];
    const float* Wv = (const float*)d_in[9];  const float* bv = (const float*)d_in[10];
    const float* Wo = (const float*)d_in[11]; const float* bo = (const float*)d_in[12];
    const float* Wd = (const float*)d_in[13]; const float* bd = (const float*)d_in[14];
    const float* Wg1 = (const float*)d_in[15]; const float* bg1 = (const float*)d_in[16];
    const float* Wg2 = (const float*)d_in[17]; const float* bg2 = (const float*)d_in[18];

    float* ws   = (float*)d_ws;
    float* q    = ws + OFF_Q;
    float* kk   = ws + OFF_K;
    float* vv   = ws + OFF_V;
    float* lg   = ws + OFF_LG;
    float* disp = ws + OFF_DISP;
    int* cnt    = (int*)(ws + OFF_CNT);
    int* rowptr = (int*)(ws + OFF_ROWPTR);
    int* cursor = (int*)(ws + OFF_CURSOR);
    int* esort  = (int*)(ws + OFF_ESORT);
    unsigned short* hhi = (unsigned short*)(ws + OFF_LG);   // dead before k_edge writes lg
    unsigned short* hlo = (unsigned short*)(ws + OFF_HLO);
    unsigned short* wsp = (unsigned short*)(ws + OFF_WSPLIT);
    int* dsort  = (int*)(ws + OFF_Q);             // q dead after k_edge
    int* loc    = (int*)(ws + OFF_Q + 500000u);
    int* bsum   = (int*)(ws + OFF_Q + 550000u);
    unsigned short* hupd_hi = (unsigned short*)(ws + OFF_K);            // k dead after k_edge
    unsigned short* hupd_lo = (unsigned short*)(ws + OFF_K + 3200000u);
    float* hout = (float*)d_out;
    float* xout = hout + (size_t)N_NODES * HIDDEN;

    const int nscan = (N_NODES + 1023) / 1024;    // 49

    k_split_h<<<6250, 256, 0, stream>>>(h, hhi, hlo);
    k_split_w<<<320, 256, 0, stream>>>(Wq, Wk, Wv, Wo, Wg1, wsp);
    k_zero_int<<<(N_NODES + 255) / 256, 256, 0, stream>>>(cnt, N_NODES);
    k_qkv_mfma<<<(N_NODES + 31) / 32, 256, 0, stream>>>(hhi, hlo, wsp, bq, bk, bv, q, kk, vv);
    k_edge<<<(N_EDGES * 8) / 256, 256, 0, stream>>>(q, kk, src, dst, dist, Wd, bd, lg, cnt);
    k_scan1<<<nscan, 1024, 0, stream>>>(cnt, loc, bsum, N_NODES);
    k_scan2<<<1, 64, 0, stream>>>(bsum, nscan);
    k_scan3<<<(N_NODES + 255) / 256, 256, 0, stream>>>(cnt, loc, bsum, rowptr, cursor, N_NODES);
    k_scatter<<<(N_EDGES + 255) / 256, 256, 0, stream>>>(src, dst, cursor, esort, dsort);
    k_node<<<N_NODES / 4, 256, 0, stream>>>(lg, vv, x, esort, dsort, rowptr,
                                            hupd_hi, hupd_lo, disp);
    k_hout_gate<<<(N_NODES + 63) / 64, 256, 0, stream>>>(h, hupd_hi, hupd_lo, wsp,
                                                         bo, bg1, Wg2, bg2,
                                                         x, disp, hout, xout);
}

// Round 5
// 373.010 us; speedup vs baseline: 1.6917x; 1.0367x over previous
//
#include <hip/hip_runtime.h>
#include <math.h>

#define N_NODES 50000
#define N_EDGES 500000
#define HIDDEN 128
#define HEADS 8
#define HEAD_DIM 16

typedef __attribute__((ext_vector_type(8))) short short8;     // 8 bf16 (4 VGPRs) MFMA A/B frag
typedef __attribute__((ext_vector_type(4))) float floatx4;    // MFMA C/D frag
typedef __attribute__((ext_vector_type(4))) unsigned short ushort4v;

// workspace layout, element offsets (4-byte units)
#define OFF_Q       0u          // loc/bsum (scan scratch, pre-qkv) -> q fp32 [50000x128]
#define OFF_K       6400000u    // k fp32; reused as hupd_hi/lo bf16 after k_edge
#define OFF_V       12800000u   // v fp32
#define OFF_LG      19200000u   // h_hi bf16 BEFORE qkv; lg [E x 8] CSR-ordered after k_edge
#define OFF_DISP    23200000u
#define OFF_CNT     23350016u
#define OFF_ROWPTR  23400032u
#define OFF_CURSOR  23450048u
#define OFF_ESORT   23500064u   // dsort [E] ints (dst gathered into CSR order)
#define OFF_HLO     24000064u   // h_lo bf16 [50000x128] = 3.2M float slots
#define OFF_WSPLIT  27200064u   // W{q,k,v,o,g1} split-bf16 frag order: 81,920 float slots
// end: 27,281,984 floats = 109.1 MB

static __device__ __forceinline__ unsigned short f2bf(float f) {
    unsigned u = __builtin_bit_cast(unsigned, f);
    unsigned r = (u + 0x7FFFu + ((u >> 16) & 1u)) >> 16;      // RNE
    return (unsigned short)r;
}
static __device__ __forceinline__ float bf2f(unsigned short s) {
    return __builtin_bit_cast(float, (unsigned)s << 16);
}

__global__ void k_zero_int(int* __restrict__ p, int n) {
    int i = blockIdx.x * 256 + threadIdx.x;
    if (i < n) p[i] = 0;
}

// split h into hi/lo bf16, row-major (grid exact: 6.4M elems / 4 per thread)
__global__ __launch_bounds__(256) void k_split_h(
    const float* __restrict__ h,
    unsigned short* __restrict__ hhi, unsigned short* __restrict__ hlo) {
    int i = (blockIdx.x * 256 + threadIdx.x) * 4;
    float4 xv = *(const float4*)(h + i);
    ushort4v hi, lo;
    float v0[4] = {xv.x, xv.y, xv.z, xv.w};
#pragma unroll
    for (int j = 0; j < 4; ++j) {
        unsigned short a = f2bf(v0[j]);
        hi[j] = a;
        lo[j] = f2bf(v0[j] - bf2f(a));
    }
    *(ushort4v*)(hhi + i) = hi;
    *(ushort4v*)(hlo + i) = lo;
}

// repack W{q,k,v,o,g1} into split-bf16 MFMA B-fragment order:
// frag(m,kc,ct,hilo): 64 lanes x 8 bf16, lane holds B[k=kc*32+(lane>>4)*8+j][n=ct*16+(lane&15)]
__global__ void k_split_w(const float* __restrict__ Wq, const float* __restrict__ Wk,
                          const float* __restrict__ Wv, const float* __restrict__ Wo,
                          const float* __restrict__ Wg1, unsigned short* __restrict__ ws) {
    int t = blockIdx.x * 256 + threadIdx.x;          // grid exact: 5*16384
    int m = t >> 14, r = t & 16383;
    int k = r >> 7, n = r & 127;
    const float* W = (m == 0) ? Wq : (m == 1) ? Wk : (m == 2) ? Wv : (m == 3) ? Wo : Wg1;
    float x = W[k * 128 + n];
    int kc = k >> 5, kin = k & 31, quad = kin >> 3, j = kin & 7;
    int ct = n >> 4, nin = n & 15, lane = quad * 16 + nin;
    unsigned base = ((((unsigned)(m * 4 + kc) * 8 + ct) * 2) * 64 + lane) * 8 + j;
    unsigned short a = f2bf(x);
    ws[base] = a;                                    // hilo=0
    ws[base + 512] = f2bf(x - bf2f(a));              // hilo=1 (+64 lanes*8)
}

// q/k/v via split-bf16 MFMA: block=256 (4 waves), 32 rows/block, wave w owns
// col-tiles {2w, 2w+1} for all 3 mats. K=128 as 4 chunks of 32.
__global__ __launch_bounds__(256) void k_qkv_mfma(
    const unsigned short* __restrict__ hhi, const unsigned short* __restrict__ hlo,
    const unsigned short* __restrict__ wsp,
    const float* __restrict__ bq, const float* __restrict__ bk, const float* __restrict__ bv,
    float* __restrict__ q, float* __restrict__ k, float* __restrict__ v) {
    const int wave = threadIdx.x >> 6, lane = threadIdx.x & 63;
    const int quad = lane >> 4, l15 = lane & 15;
    const int ct0 = wave * 2;
    const int row0 = blockIdx.x * 32;

    floatx4 acc[3][2][2];                            // [mat][ctl][rt]
#pragma unroll
    for (int m = 0; m < 3; ++m)
#pragma unroll
        for (int c = 0; c < 2; ++c)
#pragma unroll
            for (int r = 0; r < 2; ++r) acc[m][c][r] = (floatx4){0.f, 0.f, 0.f, 0.f};

#pragma unroll
    for (int kc = 0; kc < 4; ++kc) {
        short8 ah[2], al[2];
#pragma unroll
        for (int rt = 0; rt < 2; ++rt) {
            int row = row0 + rt * 16 + l15;
            if (row >= N_NODES) row = N_NODES - 1;
            size_t off = (size_t)row * 128 + kc * 32 + quad * 8;
            ah[rt] = *(const short8*)(hhi + off);
            al[rt] = *(const short8*)(hlo + off);
        }
#pragma unroll
        for (int m = 0; m < 3; ++m) {
#pragma unroll
            for (int ctl = 0; ctl < 2; ++ctl) {
                unsigned fb = ((((unsigned)(m * 4 + kc) * 8 + (ct0 + ctl)) * 2) * 64 + lane) * 8;
                short8 bh = *(const short8*)(wsp + fb);
                short8 bl = *(const short8*)(wsp + fb + 512);
#pragma unroll
                for (int rt = 0; rt < 2; ++rt) {
                    acc[m][ctl][rt] = __builtin_amdgcn_mfma_f32_16x16x32_bf16(
                        ah[rt], bh, acc[m][ctl][rt], 0, 0, 0);
                    acc[m][ctl][rt] = __builtin_amdgcn_mfma_f32_16x16x32_bf16(
                        ah[rt], bl, acc[m][ctl][rt], 0, 0, 0);
                    acc[m][ctl][rt] = __builtin_amdgcn_mfma_f32_16x16x32_bf16(
                        al[rt], bh, acc[m][ctl][rt], 0, 0, 0);
                }
            }
        }
    }

    float* outs[3] = {q, k, v};
    const float* biases[3] = {bq, bk, bv};
#pragma unroll
    for (int m = 0; m < 3; ++m) {
#pragma unroll
        for (int ctl = 0; ctl < 2; ++ctl) {
            int col = (ct0 + ctl) * 16 + l15;
            float bias = biases[m][col];
#pragma unroll
            for (int rt = 0; rt < 2; ++rt) {
#pragma unroll
                for (int reg = 0; reg < 4; ++reg) {
                    int row = row0 + rt * 16 + quad * 4 + reg;
                    if (row < N_NODES)
                        outs[m][(size_t)row * 128 + col] = acc[m][ctl][rt][reg] + bias;
                }
            }
        }
    }
}

// degree histogram
__global__ void k_count(const int* __restrict__ src, int* __restrict__ cnt) {
    int e = blockIdx.x * 256 + threadIdx.x;
    if (e < N_EDGES) atomicAdd(&cnt[src[e]], 1);
}

// hierarchical scan over 50000 counts
__global__ __launch_bounds__(1024) void k_scan1(const int* __restrict__ cnt,
                                                int* __restrict__ loc,
                                                int* __restrict__ bsum, int n) {
    __shared__ int buf[1024];
    int t = threadIdx.x;
    int i = blockIdx.x * 1024 + t;
    int val = (i < n) ? cnt[i] : 0;
    buf[t] = val;
    __syncthreads();
    for (int off = 1; off < 1024; off <<= 1) {
        int a = (t >= off) ? buf[t - off] : 0;
        __syncthreads();
        buf[t] += a;
        __syncthreads();
    }
    if (i < n) loc[i] = buf[t];
    if (t == 1023) bsum[blockIdx.x] = buf[1023];
}

__global__ void k_scan2(int* __restrict__ bsum, int nb) {
    int t = threadIdx.x;
    int v = (t < nb) ? bsum[t] : 0;
    for (int off = 1; off < 64; off <<= 1) {
        int a = __shfl_up(v, off);
        if (t >= off) v += a;
    }
    if (t < nb) bsum[t] = v;
}

__global__ void k_scan3(const int* __restrict__ cnt, const int* __restrict__ loc,
                        const int* __restrict__ bsum,
                        int* __restrict__ rowptr, int* __restrict__ cursor, int n) {
    int i = blockIdx.x * 256 + threadIdx.x;
    if (i < n) {
        int off = (i >= 1024) ? bsum[(i >> 10) - 1] : 0;
        int incl = loc[i] + off;
        rowptr[i + 1] = incl;
        cursor[i] = incl - cnt[i];
    }
    if (i == 0) rowptr[0] = 0;
}

// one thread per (edge, head): lg = q[src].k[dst]/4 - (d^2*Wd + bd),
// written directly at its CSR slot (pos from cursor atomic, shared across
// the edge's 8 head-lanes via shfl). dsort[pos] = dst.
__global__ __launch_bounds__(256) void k_edge(
    const float* __restrict__ q, const float* __restrict__ k,
    const int* __restrict__ src, const int* __restrict__ dst,
    const float* __restrict__ dist,
    const float* __restrict__ Wd, const float* __restrict__ bd,
    int* __restrict__ cursor, float* __restrict__ lg, int* __restrict__ dsort) {
    int t = blockIdx.x * 256 + threadIdx.x;   // grid exact: E*8 threads
    int e = t >> 3, hd = t & 7;
    int lane = threadIdx.x & 63;
    int s = src[e], d = dst[e];
    const float4* qp = (const float4*)(q + (size_t)s * HIDDEN + hd * HEAD_DIM);
    const float4* kp = (const float4*)(k + (size_t)d * HIDDEN + hd * HEAD_DIM);
    float dot = 0.f;
#pragma unroll
    for (int j = 0; j < 4; ++j) {
        float4 a = qp[j], b = kp[j];
        dot += a.x * b.x + a.y * b.y + a.z * b.z + a.w * b.w;
    }
    int pos = 0;
    if (hd == 0) pos = atomicAdd(&cursor[s], 1);
    pos = __shfl(pos, lane & 56);             // broadcast from hd==0 lane of this edge
    float dd = dist[e];
    lg[(size_t)pos * 8 + hd] = dot * 0.25f - (dd * dd * Wd[hd] + bd[hd]);
    if (hd == 0) dsort[pos] = d;
}

// one wave per node, SINGLE PASS (no max subtraction -- logits bounded ~|9|,
// exp(lg) safe in fp32; normalization at the end is mathematically identical).
// LDS weight buffer stride 9: reads wbuf[i*9+h] hit 8 consecutive banks
// (8-lane broadcast each) -> conflict-free; writes lane*9+j are 2-way (free).
__global__ __launch_bounds__(256) void k_node(
    const float* __restrict__ lg, const float* __restrict__ v,
    const float* __restrict__ x,
    const int* __restrict__ dsort, const int* __restrict__ rowptr,
    unsigned short* __restrict__ hupd_hi, unsigned short* __restrict__ hupd_lo,
    float* __restrict__ disp) {
    __shared__ float wbuf_all[4][576];
    const int wave = threadIdx.x >> 6, lane = threadIdx.x & 63;
    float* wbuf = wbuf_all[wave];
    const int node = blockIdx.x * 4 + wave;   // grid exact: N/4 blocks
    const int beg = rowptr[node], end = rowptr[node + 1];
    const int hp  = lane >> 3;   // head for acc lanes (dims 2*lane, 2*lane+1)
    const int hq  = lane & 7;    // head for da lanes
    const int dim = lane >> 3;   // dim for da lanes (lanes 0..23)

    float s[8] = {0.f, 0.f, 0.f, 0.f, 0.f, 0.f, 0.f, 0.f};
    float xs = 0.f;
    if (lane < 24) xs = x[node * 3 + dim];
    float acc0 = 0.f, acc1 = 0.f, da = 0.f;

    for (int cb = beg; cb < end; cb += 64) {
        int idx = cb + lane;
        int clen = min(64, end - cb);
        int d = 0;
        if (idx < end) {
            d = dsort[idx];
            const float4* lp = (const float4*)(lg + (size_t)idx * 8);  // sequential!
            float4 a = lp[0], b = lp[1];
            float wv[8];
            wv[0] = __expf(a.x); wv[1] = __expf(a.y);
            wv[2] = __expf(a.z); wv[3] = __expf(a.w);
            wv[4] = __expf(b.x); wv[5] = __expf(b.y);
            wv[6] = __expf(b.z); wv[7] = __expf(b.w);
#pragma unroll
            for (int j = 0; j < 8; ++j) {
                s[j] += wv[j];
                wbuf[lane * 9 + j] = wv[j];
            }
        }
        // same-wave LDS producer->consumer: drain LDS queue, block reordering
        __asm__ volatile("s_waitcnt lgkmcnt(0)" ::: "memory");
        for (int i = 0; i < clen; ++i) {
            int di = __shfl(d, i);
            float wa = wbuf[i * 9 + hp];
            const float2 vv = *(const float2*)(v + (size_t)di * HIDDEN + 2 * lane);
            acc0 += vv.x * wa;
            acc1 += vv.y * wa;
            if (lane < 24) {
                float wd = wbuf[i * 9 + hq];
                da += (x[di * 3 + dim] - xs) * wd;
            }
        }
        __asm__ volatile("" ::: "memory");   // keep chunk iterations ordered vs LDS reuse
    }

    for (int off = 1; off < 64; off <<= 1) {
#pragma unroll
        for (int j = 0; j < 8; ++j) s[j] += __shfl_xor(s[j], off);
    }
    float inva = 1.f / fmaxf(s[hp], 1e-9f);
    float o0 = acc0 * inva, o1 = acc1 * inva;
    unsigned short h0 = f2bf(o0), h1 = f2bf(o1);
    unsigned short l0 = f2bf(o0 - bf2f(h0)), l1 = f2bf(o1 - bf2f(h1));
    ((unsigned*)hupd_hi)[(size_t)node * 64 + lane] = (unsigned)h0 | ((unsigned)h1 << 16);
    ((unsigned*)hupd_lo)[(size_t)node * 64 + lane] = (unsigned)l0 | ((unsigned)l1 << 16);
    if (lane < 24) da *= 0.125f / fmaxf(s[hq], 1e-9f);
    da += __shfl_xor(da, 1);
    da += __shfl_xor(da, 2);
    da += __shfl_xor(da, 4);
    if (lane < 24 && hq == 0) disp[node * 3 + dim] = da;
}

// fused MFMA epilogue: hout = h + hupd@Wo + bo (GEMM1, split-bf16 MFMA);
// hout staged in per-wave padded LDS (C->A layout transpose);
// GEMM2 = hout@Wg1; gate = tanh(sum_col silu(.)*Wg2); xout = x + gate*disp.
__global__ __launch_bounds__(256) void k_hout_gate(
    const float* __restrict__ h,
    const unsigned short* __restrict__ hupd_hi, const unsigned short* __restrict__ hupd_lo,
    const unsigned short* __restrict__ wsp,
    const float* __restrict__ bo, const float* __restrict__ bg1,
    const float* __restrict__ Wg2, const float* __restrict__ bg2,
    const float* __restrict__ x, const float* __restrict__ disp,
    float* __restrict__ hout, float* __restrict__ xout) {
    __shared__ float hb[4][16 * 132];                 // +4 dword pad per row
    const int wave = threadIdx.x >> 6, lane = threadIdx.x & 63;
    const int quad = lane >> 4, l15 = lane & 15;
    const int row0 = blockIdx.x * 64 + wave * 16;
    float* hbw = hb[wave];

    // ---- GEMM1: hupd @ Wo (m=3) ----
    floatx4 acc[8];
#pragma unroll
    for (int c = 0; c < 8; ++c) acc[c] = (floatx4){0.f, 0.f, 0.f, 0.f};
#pragma unroll
    for (int kc = 0; kc < 4; ++kc) {
        int row = row0 + l15;
        if (row >= N_NODES) row = N_NODES - 1;
        size_t aoff = (size_t)row * 128 + kc * 32 + quad * 8;
        short8 ah = *(const short8*)(hupd_hi + aoff);
        short8 al = *(const short8*)(hupd_lo + aoff);
#pragma unroll
        for (int ct = 0; ct < 8; ++ct) {
            unsigned fb = ((((unsigned)(3 * 4 + kc) * 8 + ct) * 2) * 64 + lane) * 8;
            short8 bh = *(const short8*)(wsp + fb);
            short8 bl = *(const short8*)(wsp + fb + 512);
            acc[ct] = __builtin_amdgcn_mfma_f32_16x16x32_bf16(ah, bh, acc[ct], 0, 0, 0);
            acc[ct] = __builtin_amdgcn_mfma_f32_16x16x32_bf16(ah, bl, acc[ct], 0, 0, 0);
            acc[ct] = __builtin_amdgcn_mfma_f32_16x16x32_bf16(al, bh, acc[ct], 0, 0, 0);
        }
    }

    // epilogue 1: add h + bo, write hout (global) + LDS tile
#pragma unroll
    for (int ct = 0; ct < 8; ++ct) {
        int col = ct * 16 + l15;
        float bias = bo[col];
#pragma unroll
        for (int reg = 0; reg < 4; ++reg) {
            int row = row0 + quad * 4 + reg;
            float val = acc[ct][reg] + bias;
            if (row < N_NODES) {
                val += h[(size_t)row * 128 + col];
                hout[(size_t)row * 128 + col] = val;
            }
            hbw[(quad * 4 + reg) * 132 + col] = val;
        }
    }
    __asm__ volatile("s_waitcnt lgkmcnt(0)" ::: "memory");

    // ---- GEMM2: hout @ Wg1 (m=4), A-frags read from LDS ----
    floatx4 acc2[8];
#pragma unroll
    for (int c = 0; c < 8; ++c) acc2[c] = (floatx4){0.f, 0.f, 0.f, 0.f};
#pragma unroll
    for (int kc = 0; kc < 4; ++kc) {
        const float* ap = hbw + l15 * 132 + kc * 32 + quad * 8;
        float4 f0 = *(const float4*)(ap);
        float4 f1 = *(const float4*)(ap + 4);
        float fv[8] = {f0.x, f0.y, f0.z, f0.w, f1.x, f1.y, f1.z, f1.w};
        short8 ah, al;
#pragma unroll
        for (int j = 0; j < 8; ++j) {
            unsigned short hi = f2bf(fv[j]);
            ah[j] = (short)hi;
            al[j] = (short)f2bf(fv[j] - bf2f(hi));
        }
#pragma unroll
        for (int ct = 0; ct < 8; ++ct) {
            unsigned fb = ((((unsigned)(4 * 4 + kc) * 8 + ct) * 2) * 64 + lane) * 8;
            short8 bh = *(const short8*)(wsp + fb);
            short8 bl = *(const short8*)(wsp + fb + 512);
            acc2[ct] = __builtin_amdgcn_mfma_f32_16x16x32_bf16(ah, bh, acc2[ct], 0, 0, 0);
            acc2[ct] = __builtin_amdgcn_mfma_f32_16x16x32_bf16(ah, bl, acc2[ct], 0, 0, 0);
            acc2[ct] = __builtin_amdgcn_mfma_f32_16x16x32_bf16(al, bh, acc2[ct], 0, 0, 0);
        }
    }

    // epilogue 2: silu * Wg2, reduce cols -> gate -> xout
    float pr[4] = {0.f, 0.f, 0.f, 0.f};
#pragma unroll
    for (int ct = 0; ct < 8; ++ct) {
        int col = ct * 16 + l15;
        float b1 = bg1[col];
        float w2 = Wg2[col];
#pragma unroll
        for (int reg = 0; reg < 4; ++reg) {
            float z = acc2[ct][reg] + b1;
            pr[reg] += (z / (1.f + __expf(-z))) * w2;
        }
    }
#pragma unroll
    for (int off = 1; off < 16; off <<= 1) {
#pragma unroll
        for (int reg = 0; reg < 4; ++reg) pr[reg] += __shfl_xor(pr[reg], off);
    }
    if (l15 == 0) {
        float b2 = bg2[0];
#pragma unroll
        for (int reg = 0; reg < 4; ++reg) {
            int row = row0 + quad * 4 + reg;
            if (row < N_NODES) {
                float g = tanhf(pr[reg] + b2);
#pragma unroll
                for (int dd = 0; dd < 3; ++dd) {
                    int oo = row * 3 + dd;
                    xout[oo] = x[oo] + g * disp[oo];
                }
            }
        }
    }
}

extern "C" void kernel_launch(void* const* d_in, const int* in_sizes, int n_in,
                              void* d_out, int out_size, void* d_ws, size_t ws_size,
                              hipStream_t stream) {
    const float* h    = (const float*)d_in[0];
    const float* x    = (const float*)d_in[1];
    const int*   src  = (const int*)d_in[2];
    const int*   dst  = (const int*)d_in[3];
    const float* dist = (const float*)d_in[4];
    const float* Wq = (const float*)d_in[5];  const float* bq = (const float*)d_in[6];
    const float* Wk = (const float*)d_in[7];  const float* bk = (const float*)d_in[8];
    const float* Wv = (const float*)d_in[9];  const float* bv = (const float*)d_in[10];
    const float* Wo = (const float*)d_in[11]; const float* bo = (const float*)d_in[12];
    const float* Wd = (const float*)d_in[13]; const float* bd = (const float*)d_in[14];
    const float* Wg1 = (const float*)d_in[15]; const float* bg1 = (const float*)d_in[16];
    const float* Wg2 = (const float*)d_in[17]; const float* bg2 = (const float*)d_in[18];

    float* ws   = (float*)d_ws;
    float* q    = ws + OFF_Q;
    float* kk   = ws + OFF_K;
    float* vv   = ws + OFF_V;
    float* lg   = ws + OFF_LG;
    float* disp = ws + OFF_DISP;
    int* cnt    = (int*)(ws + OFF_CNT);
    int* rowptr = (int*)(ws + OFF_ROWPTR);
    int* cursor = (int*)(ws + OFF_CURSOR);
    int* dsort  = (int*)(ws + OFF_ESORT);
    unsigned short* hhi = (unsigned short*)(ws + OFF_LG);   // dead after qkv; lg overwrites
    unsigned short* hlo = (unsigned short*)(ws + OFF_HLO);
    unsigned short* wsp = (unsigned short*)(ws + OFF_WSPLIT);
    // scan scratch lives in the q region, consumed BEFORE k_qkv_mfma writes q
    int* loc    = (int*)(ws + OFF_Q);
    int* bsum   = (int*)(ws + OFF_Q + 500000u);
    unsigned short* hupd_hi = (unsigned short*)(ws + OFF_K);            // k dead after k_edge
    unsigned short* hupd_lo = (unsigned short*)(ws + OFF_K + 3200000u);
    float* hout = (float*)d_out;
    float* xout = hout + (size_t)N_NODES * HIDDEN;

    const int nscan = (N_NODES + 1023) / 1024;    // 49

    k_split_h<<<6250, 256, 0, stream>>>(h, hhi, hlo);
    k_split_w<<<320, 256, 0, stream>>>(Wq, Wk, Wv, Wo, Wg1, wsp);
    k_zero_int<<<(N_NODES + 255) / 256, 256, 0, stream>>>(cnt, N_NODES);
    k_count<<<(N_EDGES + 255) / 256, 256, 0, stream>>>(src, cnt);
    k_scan1<<<nscan, 1024, 0, stream>>>(cnt, loc, bsum, N_NODES);
    k_scan2<<<1, 64, 0, stream>>>(bsum, nscan);
    k_scan3<<<(N_NODES + 255) / 256, 256, 0, stream>>>(cnt, loc, bsum, rowptr, cursor, N_NODES);
    k_qkv_mfma<<<(N_NODES + 31) / 32, 256, 0, stream>>>(hhi, hlo, wsp, bq, bk, bv, q, kk, vv);
    k_edge<<<(N_EDGES * 8) / 256, 256, 0, stream>>>(q, kk, src, dst, dist, Wd, bd,
                                                    cursor, lg, dsort);
    k_node<<<N_NODES / 4, 256, 0, stream>>>(lg, vv, x, dsort, rowptr,
                                            hupd_hi, hupd_lo, disp);
    k_hout_gate<<<(N_NODES + 63) / 64, 256, 0, stream>>>(h, hupd_hi, hupd_lo, wsp,
                                                         bo, bg1, Wg2, bg2,
                                                         x, disp, hout, xout);
}

// Round 6
// 354.205 us; speedup vs baseline: 1.7815x; 1.0531x over previous
//
#include <hip/hip_runtime.h>
#include <math.h>

#define N_NODES 50000
#define N_EDGES 500000
#define HIDDEN 128
#define HEADS 8
#define HEAD_DIM 16

typedef __attribute__((ext_vector_type(8))) short short8;     // 8 bf16 (4 VGPRs) MFMA A/B frag
typedef __attribute__((ext_vector_type(4))) float floatx4;    // MFMA C/D frag
typedef __attribute__((ext_vector_type(4))) unsigned short ushort4v;

// workspace layout, element offsets (4-byte units)
#define OFF_Q       0u           // scan scratch (pre-qkv) -> q fp32 [50000x128]
#define OFF_K       6400000u     // k fp32 [50000x128]
#define OFF_V       12800000u    // v fp32 [50000x128]
#define OFF_HHI     19200000u    // h_hi bf16 (dead after qkv) -> hupd_hi bf16
#define OFF_HLO     22400000u    // h_lo bf16 (dead after qkv) -> hupd_lo bf16
#define OFF_DISP    25600000u    // 150,000 floats
#define OFF_CNT     25750016u    // 50,000 ints
#define OFF_ROWPTR  25800032u    // 50,001 ints
#define OFF_CURSOR  25850048u    // 50,000 ints
#define OFF_DSORT   25900064u    // 500,000 ints (dst in CSR order)
#define OFF_DIST2   26400064u    // 500,000 floats (dist^2 in CSR order)
#define OFF_WSPLIT  26900064u    // W{q,k,v,o,g1} split-bf16 frag order: 81,920 float slots
// end: 26,981,984 floats = 107.9 MB

static __device__ __forceinline__ unsigned short f2bf(float f) {
    unsigned u = __builtin_bit_cast(unsigned, f);
    unsigned r = (u + 0x7FFFu + ((u >> 16) & 1u)) >> 16;      // RNE
    return (unsigned short)r;
}
static __device__ __forceinline__ float bf2f(unsigned short s) {
    return __builtin_bit_cast(float, (unsigned)s << 16);
}

__global__ void k_zero_int(int* __restrict__ p, int n) {
    int i = blockIdx.x * 256 + threadIdx.x;
    if (i < n) p[i] = 0;
}

// split h into hi/lo bf16, row-major (grid exact: 6.4M elems / 4 per thread)
__global__ __launch_bounds__(256) void k_split_h(
    const float* __restrict__ h,
    unsigned short* __restrict__ hhi, unsigned short* __restrict__ hlo) {
    int i = (blockIdx.x * 256 + threadIdx.x) * 4;
    float4 xv = *(const float4*)(h + i);
    ushort4v hi, lo;
    float v0[4] = {xv.x, xv.y, xv.z, xv.w};
#pragma unroll
    for (int j = 0; j < 4; ++j) {
        unsigned short a = f2bf(v0[j]);
        hi[j] = a;
        lo[j] = f2bf(v0[j] - bf2f(a));
    }
    *(ushort4v*)(hhi + i) = hi;
    *(ushort4v*)(hlo + i) = lo;
}

// repack W{q,k,v,o,g1} into split-bf16 MFMA B-fragment order:
// frag(m,kc,ct,hilo): 64 lanes x 8 bf16, lane holds B[k=kc*32+(lane>>4)*8+j][n=ct*16+(lane&15)]
__global__ void k_split_w(const float* __restrict__ Wq, const float* __restrict__ Wk,
                          const float* __restrict__ Wv, const float* __restrict__ Wo,
                          const float* __restrict__ Wg1, unsigned short* __restrict__ ws) {
    int t = blockIdx.x * 256 + threadIdx.x;          // grid exact: 5*16384
    int m = t >> 14, r = t & 16383;
    int k = r >> 7, n = r & 127;
    const float* W = (m == 0) ? Wq : (m == 1) ? Wk : (m == 2) ? Wv : (m == 3) ? Wo : Wg1;
    float x = W[k * 128 + n];
    int kc = k >> 5, kin = k & 31, quad = kin >> 3, j = kin & 7;
    int ct = n >> 4, nin = n & 15, lane = quad * 16 + nin;
    unsigned base = ((((unsigned)(m * 4 + kc) * 8 + ct) * 2) * 64 + lane) * 8 + j;
    unsigned short a = f2bf(x);
    ws[base] = a;                                    // hilo=0
    ws[base + 512] = f2bf(x - bf2f(a));              // hilo=1 (+64 lanes*8)
}

// q/k/v via split-bf16 MFMA: block=256 (4 waves), 32 rows/block, wave w owns
// col-tiles {2w, 2w+1} for all 3 mats. K=128 as 4 chunks of 32.
__global__ __launch_bounds__(256) void k_qkv_mfma(
    const unsigned short* __restrict__ hhi, const unsigned short* __restrict__ hlo,
    const unsigned short* __restrict__ wsp,
    const float* __restrict__ bq, const float* __restrict__ bk, const float* __restrict__ bv,
    float* __restrict__ q, float* __restrict__ k, float* __restrict__ v) {
    const int wave = threadIdx.x >> 6, lane = threadIdx.x & 63;
    const int quad = lane >> 4, l15 = lane & 15;
    const int ct0 = wave * 2;
    const int row0 = blockIdx.x * 32;

    floatx4 acc[3][2][2];                            // [mat][ctl][rt]
#pragma unroll
    for (int m = 0; m < 3; ++m)
#pragma unroll
        for (int c = 0; c < 2; ++c)
#pragma unroll
            for (int r = 0; r < 2; ++r) acc[m][c][r] = (floatx4){0.f, 0.f, 0.f, 0.f};

#pragma unroll
    for (int kc = 0; kc < 4; ++kc) {
        short8 ah[2], al[2];
#pragma unroll
        for (int rt = 0; rt < 2; ++rt) {
            int row = row0 + rt * 16 + l15;
            if (row >= N_NODES) row = N_NODES - 1;
            size_t off = (size_t)row * 128 + kc * 32 + quad * 8;
            ah[rt] = *(const short8*)(hhi + off);
            al[rt] = *(const short8*)(hlo + off);
        }
#pragma unroll
        for (int m = 0; m < 3; ++m) {
#pragma unroll
            for (int ctl = 0; ctl < 2; ++ctl) {
                unsigned fb = ((((unsigned)(m * 4 + kc) * 8 + (ct0 + ctl)) * 2) * 64 + lane) * 8;
                short8 bh = *(const short8*)(wsp + fb);
                short8 bl = *(const short8*)(wsp + fb + 512);
#pragma unroll
                for (int rt = 0; rt < 2; ++rt) {
                    acc[m][ctl][rt] = __builtin_amdgcn_mfma_f32_16x16x32_bf16(
                        ah[rt], bh, acc[m][ctl][rt], 0, 0, 0);
                    acc[m][ctl][rt] = __builtin_amdgcn_mfma_f32_16x16x32_bf16(
                        ah[rt], bl, acc[m][ctl][rt], 0, 0, 0);
                    acc[m][ctl][rt] = __builtin_amdgcn_mfma_f32_16x16x32_bf16(
                        al[rt], bh, acc[m][ctl][rt], 0, 0, 0);
                }
            }
        }
    }

    float* outs[3] = {q, k, v};
    const float* biases[3] = {bq, bk, bv};
#pragma unroll
    for (int m = 0; m < 3; ++m) {
#pragma unroll
        for (int ctl = 0; ctl < 2; ++ctl) {
            int col = (ct0 + ctl) * 16 + l15;
            float bias = biases[m][col];
#pragma unroll
            for (int rt = 0; rt < 2; ++rt) {
#pragma unroll
                for (int reg = 0; reg < 4; ++reg) {
                    int row = row0 + rt * 16 + quad * 4 + reg;
                    if (row < N_NODES)
                        outs[m][(size_t)row * 128 + col] = acc[m][ctl][rt][reg] + bias;
                }
            }
        }
    }
}

// degree histogram
__global__ void k_count(const int* __restrict__ src, int* __restrict__ cnt) {
    int e = blockIdx.x * 256 + threadIdx.x;
    if (e < N_EDGES) atomicAdd(&cnt[src[e]], 1);
}

// hierarchical scan over 50000 counts
__global__ __launch_bounds__(1024) void k_scan1(const int* __restrict__ cnt,
                                                int* __restrict__ loc,
                                                int* __restrict__ bsum, int n) {
    __shared__ int buf[1024];
    int t = threadIdx.x;
    int i = blockIdx.x * 1024 + t;
    int val = (i < n) ? cnt[i] : 0;
    buf[t] = val;
    __syncthreads();
    for (int off = 1; off < 1024; off <<= 1) {
        int a = (t >= off) ? buf[t - off] : 0;
        __syncthreads();
        buf[t] += a;
        __syncthreads();
    }
    if (i < n) loc[i] = buf[t];
    if (t == 1023) bsum[blockIdx.x] = buf[1023];
}

__global__ void k_scan2(int* __restrict__ bsum, int nb) {
    int t = threadIdx.x;
    int v = (t < nb) ? bsum[t] : 0;
    for (int off = 1; off < 64; off <<= 1) {
        int a = __shfl_up(v, off);
        if (t >= off) v += a;
    }
    if (t < nb) bsum[t] = v;
}

__global__ void k_scan3(const int* __restrict__ cnt, const int* __restrict__ loc,
                        const int* __restrict__ bsum,
                        int* __restrict__ rowptr, int* __restrict__ cursor, int n) {
    int i = blockIdx.x * 256 + threadIdx.x;
    if (i < n) {
        int off = (i >= 1024) ? bsum[(i >> 10) - 1] : 0;
        int incl = loc[i] + off;
        rowptr[i + 1] = incl;
        cursor[i] = incl - cnt[i];
    }
    if (i == 0) rowptr[0] = 0;
}

// scatter into CSR order: dsort = dst, dist2 = dist^2
__global__ void k_scatter(const int* __restrict__ src, const int* __restrict__ dst,
                          const float* __restrict__ dist, int* __restrict__ cursor,
                          int* __restrict__ dsort, float* __restrict__ dist2) {
    int e = blockIdx.x * 256 + threadIdx.x;
    if (e < N_EDGES) {
        int pos = atomicAdd(&cursor[src[e]], 1);
        dsort[pos] = dst[e];
        float dd = dist[e];
        dist2[pos] = dd * dd;
    }
}

// FUSED edge+node: one wave per node. q row in registers (2 floats/lane);
// per edge: gather k[dst],v[dst] (float2/lane), 8 head-dots via 3 intra-group
// shfl_xor, w = exp(dot/4 - bias) (no-max trick: logits bounded ~|9|),
// accumulate sum(w), sum(w*v), per-head disp. Normalize at the end.
// No LDS, no lg buffer.
__global__ __launch_bounds__(256) void k_edge_node(
    const float* __restrict__ q, const float* __restrict__ k,
    const float* __restrict__ v, const float* __restrict__ x,
    const int* __restrict__ dsort, const float* __restrict__ dist2,
    const int* __restrict__ rowptr,
    const float* __restrict__ Wd, const float* __restrict__ bd,
    unsigned short* __restrict__ hupd_hi, unsigned short* __restrict__ hupd_lo,
    float* __restrict__ disp) {
    const int wave = threadIdx.x >> 6, lane = threadIdx.x & 63;
    const int node = blockIdx.x * 4 + wave;           // grid exact: N/4 blocks
    const int h = lane >> 3, sub = lane & 7;          // head, within-head slot
    const int beg = rowptr[node], end = rowptr[node + 1];

    const float2 qv = *(const float2*)(q + (size_t)node * 128 + 2 * lane);
    const float wdh = Wd[h], bdh = bd[h];
    float xs = (sub < 3) ? x[node * 3 + sub] : 0.f;

    float acc0 = 0.f, acc1 = 0.f, s_own = 0.f, da = 0.f;

    for (int cb = beg; cb < end; cb += 64) {
        int idx = cb + lane;
        int dvec = 0; float d2vec = 0.f;
        if (idx < end) { dvec = dsort[idx]; d2vec = dist2[idx]; }
        int clen = min(64, end - cb);
        for (int i = 0; i < clen; ++i) {
            int di = __shfl(dvec, i);
            float dd2 = __shfl(d2vec, i);
            const float2 kv = *(const float2*)(k + (size_t)di * 128 + 2 * lane);
            const float2 vv = *(const float2*)(v + (size_t)di * 128 + 2 * lane);
            float p = qv.x * kv.x + qv.y * kv.y;
            p += __shfl_xor(p, 1);
            p += __shfl_xor(p, 2);
            p += __shfl_xor(p, 4);                     // all 8 lanes of head h: full dot
            float w = __expf(p * 0.25f - (dd2 * wdh + bdh));
            s_own += w;
            acc0 += vv.x * w;
            acc1 += vv.y * w;
            if (sub < 3) da += (x[di * 3 + sub] - xs) * w;
        }
    }

    float inva = 1.f / fmaxf(s_own, 1e-9f);
    float o0 = acc0 * inva, o1 = acc1 * inva;
    unsigned short h0 = f2bf(o0), h1 = f2bf(o1);
    unsigned short l0 = f2bf(o0 - bf2f(h0)), l1 = f2bf(o1 - bf2f(h1));
    ((unsigned*)hupd_hi)[(size_t)node * 64 + lane] = (unsigned)h0 | ((unsigned)h1 << 16);
    ((unsigned*)hupd_lo)[(size_t)node * 64 + lane] = (unsigned)l0 | ((unsigned)l1 << 16);

    // disp: da is head h's unnormalized sum for dim=sub (sub<3). Normalize by
    // own head's s, mean over heads (x0.125), then sum across head groups.
    da *= 0.125f * inva;
    da += __shfl_xor(da, 8);
    da += __shfl_xor(da, 16);
    da += __shfl_xor(da, 32);
    if (lane < 3) disp[node * 3 + lane] = da;
}

// fused MFMA epilogue: hout = h + hupd@Wo + bo (GEMM1, split-bf16 MFMA);
// hout staged in per-wave padded LDS (C->A layout transpose);
// GEMM2 = hout@Wg1; gate = tanh(sum_col silu(.)*Wg2); xout = x + gate*disp.
__global__ __launch_bounds__(256) void k_hout_gate(
    const float* __restrict__ h,
    const unsigned short* __restrict__ hupd_hi, const unsigned short* __restrict__ hupd_lo,
    const unsigned short* __restrict__ wsp,
    const float* __restrict__ bo, const float* __restrict__ bg1,
    const float* __restrict__ Wg2, const float* __restrict__ bg2,
    const float* __restrict__ x, const float* __restrict__ disp,
    float* __restrict__ hout, float* __restrict__ xout) {
    __shared__ float hb[4][16 * 132];                 // +4 dword pad per row
    const int wave = threadIdx.x >> 6, lane = threadIdx.x & 63;
    const int quad = lane >> 4, l15 = lane & 15;
    const int row0 = blockIdx.x * 64 + wave * 16;
    float* hbw = hb[wave];

    // ---- GEMM1: hupd @ Wo (m=3) ----
    floatx4 acc[8];
#pragma unroll
    for (int c = 0; c < 8; ++c) acc[c] = (floatx4){0.f, 0.f, 0.f, 0.f};
#pragma unroll
    for (int kc = 0; kc < 4; ++kc) {
        int row = row0 + l15;
        if (row >= N_NODES) row = N_NODES - 1;
        size_t aoff = (size_t)row * 128 + kc * 32 + quad * 8;
        short8 ah = *(const short8*)(hupd_hi + aoff);
        short8 al = *(const short8*)(hupd_lo + aoff);
#pragma unroll
        for (int ct = 0; ct < 8; ++ct) {
            unsigned fb = ((((unsigned)(3 * 4 + kc) * 8 + ct) * 2) * 64 + lane) * 8;
            short8 bh = *(const short8*)(wsp + fb);
            short8 bl = *(const short8*)(wsp + fb + 512);
            acc[ct] = __builtin_amdgcn_mfma_f32_16x16x32_bf16(ah, bh, acc[ct], 0, 0, 0);
            acc[ct] = __builtin_amdgcn_mfma_f32_16x16x32_bf16(ah, bl, acc[ct], 0, 0, 0);
            acc[ct] = __builtin_amdgcn_mfma_f32_16x16x32_bf16(al, bh, acc[ct], 0, 0, 0);
        }
    }

    // epilogue 1: add h + bo, write hout (global) + LDS tile
#pragma unroll
    for (int ct = 0; ct < 8; ++ct) {
        int col = ct * 16 + l15;
        float bias = bo[col];
#pragma unroll
        for (int reg = 0; reg < 4; ++reg) {
            int row = row0 + quad * 4 + reg;
            float val = acc[ct][reg] + bias;
            if (row < N_NODES) {
                val += h[(size_t)row * 128 + col];
                hout[(size_t)row * 128 + col] = val;
            }
            hbw[(quad * 4 + reg) * 132 + col] = val;
        }
    }
    __asm__ volatile("s_waitcnt lgkmcnt(0)" ::: "memory");

    // ---- GEMM2: hout @ Wg1 (m=4), A-frags read from LDS ----
    floatx4 acc2[8];
#pragma unroll
    for (int c = 0; c < 8; ++c) acc2[c] = (floatx4){0.f, 0.f, 0.f, 0.f};
#pragma unroll
    for (int kc = 0; kc < 4; ++kc) {
        const float* ap = hbw + l15 * 132 + kc * 32 + quad * 8;
        float4 f0 = *(const float4*)(ap);
        float4 f1 = *(const float4*)(ap + 4);
        float fv[8] = {f0.x, f0.y, f0.z, f0.w, f1.x, f1.y, f1.z, f1.w};
        short8 ah, al;
#pragma unroll
        for (int j = 0; j < 8; ++j) {
            unsigned short hi = f2bf(fv[j]);
            ah[j] = (short)hi;
            al[j] = (short)f2bf(fv[j] - bf2f(hi));
        }
#pragma unroll
        for (int ct = 0; ct < 8; ++ct) {
            unsigned fb = ((((unsigned)(4 * 4 + kc) * 8 + ct) * 2) * 64 + lane) * 8;
            short8 bh = *(const short8*)(wsp + fb);
            short8 bl = *(const short8*)(wsp + fb + 512);
            acc2[ct] = __builtin_amdgcn_mfma_f32_16x16x32_bf16(ah, bh, acc2[ct], 0, 0, 0);
            acc2[ct] = __builtin_amdgcn_mfma_f32_16x16x32_bf16(ah, bl, acc2[ct], 0, 0, 0);
            acc2[ct] = __builtin_amdgcn_mfma_f32_16x16x32_bf16(al, bh, acc2[ct], 0, 0, 0);
        }
    }

    // epilogue 2: silu * Wg2, reduce cols -> gate -> xout
    float pr[4] = {0.f, 0.f, 0.f, 0.f};
#pragma unroll
    for (int ct = 0; ct < 8; ++ct) {
        int col = ct * 16 + l15;
        float b1 = bg1[col];
        float w2 = Wg2[col];
#pragma unroll
        for (int reg = 0; reg < 4; ++reg) {
            float z = acc2[ct][reg] + b1;
            pr[reg] += (z / (1.f + __expf(-z))) * w2;
        }
    }
#pragma unroll
    for (int off = 1; off < 16; off <<= 1) {
#pragma unroll
        for (int reg = 0; reg < 4; ++reg) pr[reg] += __shfl_xor(pr[reg], off);
    }
    if (l15 == 0) {
        float b2 = bg2[0];
#pragma unroll
        for (int reg = 0; reg < 4; ++reg) {
            int row = row0 + quad * 4 + reg;
            if (row < N_NODES) {
                float g = tanhf(pr[reg] + b2);
#pragma unroll
                for (int dd = 0; dd < 3; ++dd) {
                    int oo = row * 3 + dd;
                    xout[oo] = x[oo] + g * disp[oo];
                }
            }
        }
    }
}

extern "C" void kernel_launch(void* const* d_in, const int* in_sizes, int n_in,
                              void* d_out, int out_size, void* d_ws, size_t ws_size,
                              hipStream_t stream) {
    const float* h    = (const float*)d_in[0];
    const float* x    = (const float*)d_in[1];
    const int*   src  = (const int*)d_in[2];
    const int*   dst  = (const int*)d_in[3];
    const float* dist = (const float*)d_in[4];
    const float* Wq = (const float*)d_in[5];  const float* bq = (const float*)d_in[6];
    const float* Wk = (const float*)d_in[7];  const float* bk = (const float*)d_in[8];
    const float* Wv = (const float*)d_in[9];  const float* bv = (const float*)d_in[10];
    const float* Wo = (const float*)d_in[11]; const float* bo = (const float*)d_in[12];
    const float* Wd = (const float*)d_in[13]; const float* bd = (const float*)d_in[14];
    const float* Wg1 = (const float*)d_in[15]; const float* bg1 = (const float*)d_in[16];
    const float* Wg2 = (const float*)d_in[17]; const float* bg2 = (const float*)d_in[18];

    float* ws    = (float*)d_ws;
    float* q     = ws + OFF_Q;
    float* kk    = ws + OFF_K;
    float* vv    = ws + OFF_V;
    float* disp  = ws + OFF_DISP;
    int* cnt     = (int*)(ws + OFF_CNT);
    int* rowptr  = (int*)(ws + OFF_ROWPTR);
    int* cursor  = (int*)(ws + OFF_CURSOR);
    int* dsort   = (int*)(ws + OFF_DSORT);
    float* dist2 = ws + OFF_DIST2;
    unsigned short* hhi = (unsigned short*)(ws + OFF_HHI);
    unsigned short* hlo = (unsigned short*)(ws + OFF_HLO);
    unsigned short* wsp = (unsigned short*)(ws + OFF_WSPLIT);
    // scan scratch in q region, consumed before k_qkv_mfma writes q
    int* loc    = (int*)(ws + OFF_Q);
    int* bsum   = (int*)(ws + OFF_Q + 500000u);
    // hupd reuses hhi/hlo regions (dead after k_qkv_mfma)
    unsigned short* hupd_hi = (unsigned short*)(ws + OFF_HHI);
    unsigned short* hupd_lo = (unsigned short*)(ws + OFF_HLO);
    float* hout = (float*)d_out;
    float* xout = hout + (size_t)N_NODES * HIDDEN;

    const int nscan = (N_NODES + 1023) / 1024;    // 49

    k_split_h<<<6250, 256, 0, stream>>>(h, hhi, hlo);
    k_split_w<<<320, 256, 0, stream>>>(Wq, Wk, Wv, Wo, Wg1, wsp);
    k_zero_int<<<(N_NODES + 255) / 256, 256, 0, stream>>>(cnt, N_NODES);
    k_count<<<(N_EDGES + 255) / 256, 256, 0, stream>>>(src, cnt);
    k_scan1<<<nscan, 1024, 0, stream>>>(cnt, loc, bsum, N_NODES);
    k_scan2<<<1, 64, 0, stream>>>(bsum, nscan);
    k_scan3<<<(N_NODES + 255) / 256, 256, 0, stream>>>(cnt, loc, bsum, rowptr, cursor, N_NODES);
    k_scatter<<<(N_EDGES + 255) / 256, 256, 0, stream>>>(src, dst, dist, cursor, dsort, dist2);
    k_qkv_mfma<<<(N_NODES + 31) / 32, 256, 0, stream>>>(hhi, hlo, wsp, bq, bk, bv, q, kk, vv);
    k_edge_node<<<N_NODES / 4, 256, 0, stream>>>(q, kk, vv, x, dsort, dist2, rowptr,
                                                 Wd, bd, hupd_hi, hupd_lo, disp);
    k_hout_gate<<<(N_NODES + 63) / 64, 256, 0, stream>>>(h, hupd_hi, hupd_lo, wsp,
                                                         bo, bg1, Wg2, bg2,
                                                         x, disp, hout, xout);
}

// Round 7
// 324.409 us; speedup vs baseline: 1.9452x; 1.0918x over previous
//
#include <hip/hip_runtime.h>
#include <math.h>

#define N_NODES 50000
#define N_EDGES 500000
#define HIDDEN 128
#define HEADS 8
#define HEAD_DIM 16

typedef __attribute__((ext_vector_type(8))) short short8;     // 8 bf16 (4 VGPRs) MFMA A/B frag
typedef __attribute__((ext_vector_type(4))) float floatx4;    // MFMA C/D frag
typedef __attribute__((ext_vector_type(4))) unsigned short ushort4v;

// workspace layout, element offsets (4-byte units)
#define OFF_Q       0u           // scan scratch (pre-qkv) -> q fp32 [50000x128]
#define OFF_KV      6400000u     // kv packed bf16 pairs [50000x128] (k lo16, v hi16)
#define OFF_HHI     12800000u    // h_hi bf16 (dead after qkv) -> hupd_hi bf16
#define OFF_HLO     16000000u    // h_lo bf16 (dead after qkv) -> hupd_lo bf16
#define OFF_DISP    19200000u    // 150,000 floats
#define OFF_CNT     19350016u    // 50,000 ints
#define OFF_ROWPTR  19400032u    // 50,001 ints
#define OFF_CURSOR  19450048u    // 50,000 ints
#define OFF_ESD     19500064u    // 1,000,000 ints (int2 per edge: dst, dist^2 bits, CSR order)
#define OFF_WSPLIT  20500064u    // W{q,k,v,o,g1} split-bf16 frag order: 81,920 float slots
// end: 20,581,984 floats = 82.3 MB

static __device__ __forceinline__ unsigned short f2bf(float f) {
    unsigned u = __builtin_bit_cast(unsigned, f);
    unsigned r = (u + 0x7FFFu + ((u >> 16) & 1u)) >> 16;      // RNE
    return (unsigned short)r;
}
static __device__ __forceinline__ float bf2f(unsigned short s) {
    return __builtin_bit_cast(float, (unsigned)s << 16);
}

__global__ void k_zero_int(int* __restrict__ p, int n) {
    int i = blockIdx.x * 256 + threadIdx.x;
    if (i < n) p[i] = 0;
}

// split h into hi/lo bf16, row-major (grid exact: 6.4M elems / 4 per thread)
__global__ __launch_bounds__(256) void k_split_h(
    const float* __restrict__ h,
    unsigned short* __restrict__ hhi, unsigned short* __restrict__ hlo) {
    int i = (blockIdx.x * 256 + threadIdx.x) * 4;
    float4 xv = *(const float4*)(h + i);
    ushort4v hi, lo;
    float v0[4] = {xv.x, xv.y, xv.z, xv.w};
#pragma unroll
    for (int j = 0; j < 4; ++j) {
        unsigned short a = f2bf(v0[j]);
        hi[j] = a;
        lo[j] = f2bf(v0[j] - bf2f(a));
    }
    *(ushort4v*)(hhi + i) = hi;
    *(ushort4v*)(hlo + i) = lo;
}

// repack W{q,k,v,o,g1} into split-bf16 MFMA B-fragment order:
// frag(m,kc,ct,hilo): 64 lanes x 8 bf16, lane holds B[k=kc*32+(lane>>4)*8+j][n=ct*16+(lane&15)]
__global__ void k_split_w(const float* __restrict__ Wq, const float* __restrict__ Wk,
                          const float* __restrict__ Wv, const float* __restrict__ Wo,
                          const float* __restrict__ Wg1, unsigned short* __restrict__ ws) {
    int t = blockIdx.x * 256 + threadIdx.x;          // grid exact: 5*16384
    int m = t >> 14, r = t & 16383;
    int k = r >> 7, n = r & 127;
    const float* W = (m == 0) ? Wq : (m == 1) ? Wk : (m == 2) ? Wv : (m == 3) ? Wo : Wg1;
    float x = W[k * 128 + n];
    int kc = k >> 5, kin = k & 31, quad = kin >> 3, j = kin & 7;
    int ct = n >> 4, nin = n & 15, lane = quad * 16 + nin;
    unsigned base = ((((unsigned)(m * 4 + kc) * 8 + ct) * 2) * 64 + lane) * 8 + j;
    unsigned short a = f2bf(x);
    ws[base] = a;                                    // hilo=0
    ws[base + 512] = f2bf(x - bf2f(a));              // hilo=1 (+64 lanes*8)
}

// q/k/v via split-bf16 MFMA. q written fp32; k,v packed as bf16 pairs
// (k in lo16, v in hi16) -> single gather array for the edge phase.
__global__ __launch_bounds__(256) void k_qkv_mfma(
    const unsigned short* __restrict__ hhi, const unsigned short* __restrict__ hlo,
    const unsigned short* __restrict__ wsp,
    const float* __restrict__ bq, const float* __restrict__ bk, const float* __restrict__ bv,
    float* __restrict__ q, unsigned* __restrict__ kvp) {
    const int wave = threadIdx.x >> 6, lane = threadIdx.x & 63;
    const int quad = lane >> 4, l15 = lane & 15;
    const int ct0 = wave * 2;
    const int row0 = blockIdx.x * 32;

    floatx4 acc[3][2][2];                            // [mat][ctl][rt]
#pragma unroll
    for (int m = 0; m < 3; ++m)
#pragma unroll
        for (int c = 0; c < 2; ++c)
#pragma unroll
            for (int r = 0; r < 2; ++r) acc[m][c][r] = (floatx4){0.f, 0.f, 0.f, 0.f};

#pragma unroll
    for (int kc = 0; kc < 4; ++kc) {
        short8 ah[2], al[2];
#pragma unroll
        for (int rt = 0; rt < 2; ++rt) {
            int row = row0 + rt * 16 + l15;
            if (row >= N_NODES) row = N_NODES - 1;
            size_t off = (size_t)row * 128 + kc * 32 + quad * 8;
            ah[rt] = *(const short8*)(hhi + off);
            al[rt] = *(const short8*)(hlo + off);
        }
#pragma unroll
        for (int m = 0; m < 3; ++m) {
#pragma unroll
            for (int ctl = 0; ctl < 2; ++ctl) {
                unsigned fb = ((((unsigned)(m * 4 + kc) * 8 + (ct0 + ctl)) * 2) * 64 + lane) * 8;
                short8 bh = *(const short8*)(wsp + fb);
                short8 bl = *(const short8*)(wsp + fb + 512);
#pragma unroll
                for (int rt = 0; rt < 2; ++rt) {
                    acc[m][ctl][rt] = __builtin_amdgcn_mfma_f32_16x16x32_bf16(
                        ah[rt], bh, acc[m][ctl][rt], 0, 0, 0);
                    acc[m][ctl][rt] = __builtin_amdgcn_mfma_f32_16x16x32_bf16(
                        ah[rt], bl, acc[m][ctl][rt], 0, 0, 0);
                    acc[m][ctl][rt] = __builtin_amdgcn_mfma_f32_16x16x32_bf16(
                        al[rt], bh, acc[m][ctl][rt], 0, 0, 0);
                }
            }
        }
    }

#pragma unroll
    for (int ctl = 0; ctl < 2; ++ctl) {
        int col = (ct0 + ctl) * 16 + l15;
        float bq_ = bq[col], bk_ = bk[col], bv_ = bv[col];
#pragma unroll
        for (int rt = 0; rt < 2; ++rt) {
#pragma unroll
            for (int reg = 0; reg < 4; ++reg) {
                int row = row0 + rt * 16 + quad * 4 + reg;
                if (row < N_NODES) {
                    q[(size_t)row * 128 + col] = acc[0][ctl][rt][reg] + bq_;
                    unsigned kb = f2bf(acc[1][ctl][rt][reg] + bk_);
                    unsigned vb = f2bf(acc[2][ctl][rt][reg] + bv_);
                    kvp[(size_t)row * 128 + col] = kb | (vb << 16);
                }
            }
        }
    }
}

// degree histogram
__global__ void k_count(const int* __restrict__ src, int* __restrict__ cnt) {
    int e = blockIdx.x * 256 + threadIdx.x;
    if (e < N_EDGES) atomicAdd(&cnt[src[e]], 1);
}

// hierarchical scan over 50000 counts
__global__ __launch_bounds__(1024) void k_scan1(const int* __restrict__ cnt,
                                                int* __restrict__ loc,
                                                int* __restrict__ bsum, int n) {
    __shared__ int buf[1024];
    int t = threadIdx.x;
    int i = blockIdx.x * 1024 + t;
    int val = (i < n) ? cnt[i] : 0;
    buf[t] = val;
    __syncthreads();
    for (int off = 1; off < 1024; off <<= 1) {
        int a = (t >= off) ? buf[t - off] : 0;
        __syncthreads();
        buf[t] += a;
        __syncthreads();
    }
    if (i < n) loc[i] = buf[t];
    if (t == 1023) bsum[blockIdx.x] = buf[1023];
}

__global__ void k_scan2(int* __restrict__ bsum, int nb) {
    int t = threadIdx.x;
    int v = (t < nb) ? bsum[t] : 0;
    for (int off = 1; off < 64; off <<= 1) {
        int a = __shfl_up(v, off);
        if (t >= off) v += a;
    }
    if (t < nb) bsum[t] = v;
}

__global__ void k_scan3(const int* __restrict__ cnt, const int* __restrict__ loc,
                        const int* __restrict__ bsum,
                        int* __restrict__ rowptr, int* __restrict__ cursor, int n) {
    int i = blockIdx.x * 256 + threadIdx.x;
    if (i < n) {
        int off = (i >= 1024) ? bsum[(i >> 10) - 1] : 0;
        int incl = loc[i] + off;
        rowptr[i + 1] = incl;
        cursor[i] = incl - cnt[i];
    }
    if (i == 0) rowptr[0] = 0;
}

// scatter into CSR order: esd[pos] = (dst, dist^2) as one 8B store
__global__ void k_scatter(const int* __restrict__ src, const int* __restrict__ dst,
                          const float* __restrict__ dist, int* __restrict__ cursor,
                          int2* __restrict__ esd) {
    int e = blockIdx.x * 256 + threadIdx.x;
    if (e < N_EDGES) {
        int pos = atomicAdd(&cursor[src[e]], 1);
        float dd = dist[e];
        esd[pos] = make_int2(dst[e], __float_as_int(dd * dd));
    }
}

// FUSED edge+node: one wave per node. q row in registers (2 floats/lane);
// per edge: ONE gather of the packed bf16 kv row (uint2/lane = cols 2l,2l+1),
// unpack k via <<16, v via mask; 8 head-dots via 3 intra-group shfl_xor;
// w = exp(dot/4 - bias) (no-max trick: logits bounded); accumulate
// sum(w), sum(w*v), per-head disp. Normalize at the end.
__global__ __launch_bounds__(256) void k_edge_node(
    const float* __restrict__ q, const unsigned* __restrict__ kvp,
    const float* __restrict__ x,
    const int2* __restrict__ esd, const int* __restrict__ rowptr,
    const float* __restrict__ Wd, const float* __restrict__ bd,
    unsigned short* __restrict__ hupd_hi, unsigned short* __restrict__ hupd_lo,
    float* __restrict__ disp) {
    const int wave = threadIdx.x >> 6, lane = threadIdx.x & 63;
    const int node = blockIdx.x * 4 + wave;           // grid exact: N/4 blocks
    const int h = lane >> 3, sub = lane & 7;          // head, within-head slot
    const int beg = rowptr[node], end = rowptr[node + 1];

    const float2 qv = *(const float2*)(q + (size_t)node * 128 + 2 * lane);
    const float wdh = Wd[h], bdh = bd[h];
    float xs = (sub < 3) ? x[node * 3 + sub] : 0.f;

    float acc0 = 0.f, acc1 = 0.f, s_own = 0.f, da = 0.f;

    for (int cb = beg; cb < end; cb += 64) {
        int idx = cb + lane;
        int dvec = 0; float d2vec = 0.f;
        if (idx < end) {
            int2 ed = esd[idx];
            dvec = ed.x;
            d2vec = __int_as_float(ed.y);
        }
        int clen = min(64, end - cb);
        for (int i = 0; i < clen; ++i) {
            int di = __shfl(dvec, i);
            float dd2 = __shfl(d2vec, i);
            const uint2 kv2 = *(const uint2*)(kvp + (size_t)di * 128 + 2 * lane);
            float k0 = __builtin_bit_cast(float, kv2.x << 16);
            float v0 = __builtin_bit_cast(float, kv2.x & 0xFFFF0000u);
            float k1 = __builtin_bit_cast(float, kv2.y << 16);
            float v1 = __builtin_bit_cast(float, kv2.y & 0xFFFF0000u);
            float p = qv.x * k0 + qv.y * k1;
            p += __shfl_xor(p, 1);
            p += __shfl_xor(p, 2);
            p += __shfl_xor(p, 4);                     // all 8 lanes of head h: full dot
            float w = __expf(p * 0.25f - (dd2 * wdh + bdh));
            s_own += w;
            acc0 += v0 * w;
            acc1 += v1 * w;
            if (sub < 3) da += (x[di * 3 + sub] - xs) * w;
        }
    }

    float inva = 1.f / fmaxf(s_own, 1e-9f);
    float o0 = acc0 * inva, o1 = acc1 * inva;
    unsigned short h0 = f2bf(o0), h1 = f2bf(o1);
    unsigned short l0 = f2bf(o0 - bf2f(h0)), l1 = f2bf(o1 - bf2f(h1));
    ((unsigned*)hupd_hi)[(size_t)node * 64 + lane] = (unsigned)h0 | ((unsigned)h1 << 16);
    ((unsigned*)hupd_lo)[(size_t)node * 64 + lane] = (unsigned)l0 | ((unsigned)l1 << 16);

    // disp: da is head h's unnormalized sum for dim=sub (sub<3). Normalize by
    // own head's s, mean over heads (x0.125), then sum across head groups.
    da *= 0.125f * inva;
    da += __shfl_xor(da, 8);
    da += __shfl_xor(da, 16);
    da += __shfl_xor(da, 32);
    if (lane < 3) disp[node * 3 + lane] = da;
}

// fused MFMA epilogue: hout = h + hupd@Wo + bo (GEMM1, split-bf16 MFMA);
// hout staged in per-wave padded LDS (C->A layout transpose);
// GEMM2 = hout@Wg1; gate = tanh(sum_col silu(.)*Wg2); xout = x + gate*disp.
__global__ __launch_bounds__(256) void k_hout_gate(
    const float* __restrict__ h,
    const unsigned short* __restrict__ hupd_hi, const unsigned short* __restrict__ hupd_lo,
    const unsigned short* __restrict__ wsp,
    const float* __restrict__ bo, const float* __restrict__ bg1,
    const float* __restrict__ Wg2, const float* __restrict__ bg2,
    const float* __restrict__ x, const float* __restrict__ disp,
    float* __restrict__ hout, float* __restrict__ xout) {
    __shared__ float hb[4][16 * 132];                 // +4 dword pad per row
    const int wave = threadIdx.x >> 6, lane = threadIdx.x & 63;
    const int quad = lane >> 4, l15 = lane & 15;
    const int row0 = blockIdx.x * 64 + wave * 16;
    float* hbw = hb[wave];

    // ---- GEMM1: hupd @ Wo (m=3) ----
    floatx4 acc[8];
#pragma unroll
    for (int c = 0; c < 8; ++c) acc[c] = (floatx4){0.f, 0.f, 0.f, 0.f};
#pragma unroll
    for (int kc = 0; kc < 4; ++kc) {
        int row = row0 + l15;
        if (row >= N_NODES) row = N_NODES - 1;
        size_t aoff = (size_t)row * 128 + kc * 32 + quad * 8;
        short8 ah = *(const short8*)(hupd_hi + aoff);
        short8 al = *(const short8*)(hupd_lo + aoff);
#pragma unroll
        for (int ct = 0; ct < 8; ++ct) {
            unsigned fb = ((((unsigned)(3 * 4 + kc) * 8 + ct) * 2) * 64 + lane) * 8;
            short8 bh = *(const short8*)(wsp + fb);
            short8 bl = *(const short8*)(wsp + fb + 512);
            acc[ct] = __builtin_amdgcn_mfma_f32_16x16x32_bf16(ah, bh, acc[ct], 0, 0, 0);
            acc[ct] = __builtin_amdgcn_mfma_f32_16x16x32_bf16(ah, bl, acc[ct], 0, 0, 0);
            acc[ct] = __builtin_amdgcn_mfma_f32_16x16x32_bf16(al, bh, acc[ct], 0, 0, 0);
        }
    }

    // epilogue 1: add h + bo, write hout (global) + LDS tile
#pragma unroll
    for (int ct = 0; ct < 8; ++ct) {
        int col = ct * 16 + l15;
        float bias = bo[col];
#pragma unroll
        for (int reg = 0; reg < 4; ++reg) {
            int row = row0 + quad * 4 + reg;
            float val = acc[ct][reg] + bias;
            if (row < N_NODES) {
                val += h[(size_t)row * 128 + col];
                hout[(size_t)row * 128 + col] = val;
            }
            hbw[(quad * 4 + reg) * 132 + col] = val;
        }
    }
    __asm__ volatile("s_waitcnt lgkmcnt(0)" ::: "memory");

    // ---- GEMM2: hout @ Wg1 (m=4), A-frags read from LDS ----
    floatx4 acc2[8];
#pragma unroll
    for (int c = 0; c < 8; ++c) acc2[c] = (floatx4){0.f, 0.f, 0.f, 0.f};
#pragma unroll
    for (int kc = 0; kc < 4; ++kc) {
        const float* ap = hbw + l15 * 132 + kc * 32 + quad * 8;
        float4 f0 = *(const float4*)(ap);
        float4 f1 = *(const float4*)(ap + 4);
        float fv[8] = {f0.x, f0.y, f0.z, f0.w, f1.x, f1.y, f1.z, f1.w};
        short8 ah, al;
#pragma unroll
        for (int j = 0; j < 8; ++j) {
            unsigned short hi = f2bf(fv[j]);
            ah[j] = (short)hi;
            al[j] = (short)f2bf(fv[j] - bf2f(hi));
        }
#pragma unroll
        for (int ct = 0; ct < 8; ++ct) {
            unsigned fb = ((((unsigned)(4 * 4 + kc) * 8 + ct) * 2) * 64 + lane) * 8;
            short8 bh = *(const short8*)(wsp + fb);
            short8 bl = *(const short8*)(wsp + fb + 512);
            acc2[ct] = __builtin_amdgcn_mfma_f32_16x16x32_bf16(ah, bh, acc2[ct], 0, 0, 0);
            acc2[ct] = __builtin_amdgcn_mfma_f32_16x16x32_bf16(ah, bl, acc2[ct], 0, 0, 0);
            acc2[ct] = __builtin_amdgcn_mfma_f32_16x16x32_bf16(al, bh, acc2[ct], 0, 0, 0);
        }
    }

    // epilogue 2: silu * Wg2, reduce cols -> gate -> xout
    float pr[4] = {0.f, 0.f, 0.f, 0.f};
#pragma unroll
    for (int ct = 0; ct < 8; ++ct) {
        int col = ct * 16 + l15;
        float b1 = bg1[col];
        float w2 = Wg2[col];
#pragma unroll
        for (int reg = 0; reg < 4; ++reg) {
            float z = acc2[ct][reg] + b1;
            pr[reg] += (z / (1.f + __expf(-z))) * w2;
        }
    }
#pragma unroll
    for (int off = 1; off < 16; off <<= 1) {
#pragma unroll
        for (int reg = 0; reg < 4; ++reg) pr[reg] += __shfl_xor(pr[reg], off);
    }
    if (l15 == 0) {
        float b2 = bg2[0];
#pragma unroll
        for (int reg = 0; reg < 4; ++reg) {
            int row = row0 + quad * 4 + reg;
            if (row < N_NODES) {
                float g = tanhf(pr[reg] + b2);
#pragma unroll
                for (int dd = 0; dd < 3; ++dd) {
                    int oo = row * 3 + dd;
                    xout[oo] = x[oo] + g * disp[oo];
                }
            }
        }
    }
}

extern "C" void kernel_launch(void* const* d_in, const int* in_sizes, int n_in,
                              void* d_out, int out_size, void* d_ws, size_t ws_size,
                              hipStream_t stream) {
    const float* h    = (const float*)d_in[0];
    const float* x    = (const float*)d_in[1];
    const int*   src  = (const int*)d_in[2];
    const int*   dst  = (const int*)d_in[3];
    const float* dist = (const float*)d_in[4];
    const float* Wq = (const float*)d_in[5];  const float* bq = (const float*)d_in[6];
    const float* Wk = (const float*)d_in[7];  const float* bk = (const float*)d_in[8];
    const float* Wv = (const float*)d_in[9];  const float* bv = (const float*)d_in[10];
    const float* Wo = (const float*)d_in[11]; const float* bo = (const float*)d_in[12];
    const float* Wd = (const float*)d_in[13]; const float* bd = (const float*)d_in[14];
    const float* Wg1 = (const float*)d_in[15]; const float* bg1 = (const float*)d_in[16];
    const float* Wg2 = (const float*)d_in[17]; const float* bg2 = (const float*)d_in[18];

    float* ws    = (float*)d_ws;
    float* q     = ws + OFF_Q;
    unsigned* kvp = (unsigned*)(ws + OFF_KV);
    float* disp  = ws + OFF_DISP;
    int* cnt     = (int*)(ws + OFF_CNT);
    int* rowptr  = (int*)(ws + OFF_ROWPTR);
    int* cursor  = (int*)(ws + OFF_CURSOR);
    int2* esd    = (int2*)(ws + OFF_ESD);
    unsigned short* hhi = (unsigned short*)(ws + OFF_HHI);
    unsigned short* hlo = (unsigned short*)(ws + OFF_HLO);
    unsigned short* wsp = (unsigned short*)(ws + OFF_WSPLIT);
    // scan scratch in q region, consumed before k_qkv_mfma writes q
    int* loc    = (int*)(ws + OFF_Q);
    int* bsum   = (int*)(ws + OFF_Q + 500000u);
    // hupd reuses hhi/hlo regions (dead after k_qkv_mfma)
    unsigned short* hupd_hi = (unsigned short*)(ws + OFF_HHI);
    unsigned short* hupd_lo = (unsigned short*)(ws + OFF_HLO);
    float* hout = (float*)d_out;
    float* xout = hout + (size_t)N_NODES * HIDDEN;

    const int nscan = (N_NODES + 1023) / 1024;    // 49

    k_split_h<<<6250, 256, 0, stream>>>(h, hhi, hlo);
    k_split_w<<<320, 256, 0, stream>>>(Wq, Wk, Wv, Wo, Wg1, wsp);
    k_zero_int<<<(N_NODES + 255) / 256, 256, 0, stream>>>(cnt, N_NODES);
    k_count<<<(N_EDGES + 255) / 256, 256, 0, stream>>>(src, cnt);
    k_scan1<<<nscan, 1024, 0, stream>>>(cnt, loc, bsum, N_NODES);
    k_scan2<<<1, 64, 0, stream>>>(bsum, nscan);
    k_scan3<<<(N_NODES + 255) / 256, 256, 0, stream>>>(cnt, loc, bsum, rowptr, cursor, N_NODES);
    k_scatter<<<(N_EDGES + 255) / 256, 256, 0, stream>>>(src, dst, dist, cursor, esd);
    k_qkv_mfma<<<(N_NODES + 31) / 32, 256, 0, stream>>>(hhi, hlo, wsp, bq, bk, bv, q, kvp);
    k_edge_node<<<N_NODES / 4, 256, 0, stream>>>(q, kvp, x, esd, rowptr,
                                                 Wd, bd, hupd_hi, hupd_lo, disp);
    k_hout_gate<<<(N_NODES + 63) / 64, 256, 0, stream>>>(h, hupd_hi, hupd_lo, wsp,
                                                         bo, bg1, Wg2, bg2,
                                                         x, disp, hout, xout);
}

// Round 8
// 293.274 us; speedup vs baseline: 2.1517x; 1.1062x over previous
//
#include <hip/hip_runtime.h>
#include <math.h>

#define N_NODES 50000
#define N_EDGES 500000
#define HIDDEN 128
#define HEADS 8
#define HEAD_DIM 16

typedef __attribute__((ext_vector_type(8))) short short8;     // 8 bf16 (4 VGPRs) MFMA A/B frag
typedef __attribute__((ext_vector_type(4))) float floatx4;    // MFMA C/D frag
typedef __attribute__((ext_vector_type(4))) unsigned short ushort4v;

// workspace layout, element offsets (4-byte units)
#define OFF_Q       0u           // scan scratch (pre-qkv) -> q fp32 [50000x128]
#define OFF_KV      6400000u     // kv packed bf16 pairs [50000x128] (k lo16, v hi16)
#define OFF_HHI     12800000u    // h_hi bf16 (dead after qkv) -> hupd_hi bf16
#define OFF_HLO     16000000u    // h_lo bf16 (dead after qkv) -> hupd_lo bf16
#define OFF_DISP    19200000u    // 150,000 floats
#define OFF_CNT     19350016u    // 50,000 ints
#define OFF_ROWPTR  19400032u    // 50,001 ints
#define OFF_CURSOR  19450048u    // 50,000 ints
#define OFF_ESD     19500064u    // 1,000,000 ints (int2 per edge: dst, dist^2 bits, CSR order)
#define OFF_WSPLIT  20500064u    // W{q,k,v,o,g1} split-bf16 frag order: 81,920 float slots
// end: 20,581,984 floats = 82.3 MB

static __device__ __forceinline__ unsigned short f2bf(float f) {
    unsigned u = __builtin_bit_cast(unsigned, f);
    unsigned r = (u + 0x7FFFu + ((u >> 16) & 1u)) >> 16;      // RNE
    return (unsigned short)r;
}
static __device__ __forceinline__ float bf2f(unsigned short s) {
    return __builtin_bit_cast(float, (unsigned)s << 16);
}

__global__ void k_zero_int(int* __restrict__ p, int n) {
    int i = blockIdx.x * 256 + threadIdx.x;
    if (i < n) p[i] = 0;
}

// split h into hi/lo bf16, row-major (grid exact: 6.4M elems / 4 per thread)
__global__ __launch_bounds__(256) void k_split_h(
    const float* __restrict__ h,
    unsigned short* __restrict__ hhi, unsigned short* __restrict__ hlo) {
    int i = (blockIdx.x * 256 + threadIdx.x) * 4;
    float4 xv = *(const float4*)(h + i);
    ushort4v hi, lo;
    float v0[4] = {xv.x, xv.y, xv.z, xv.w};
#pragma unroll
    for (int j = 0; j < 4; ++j) {
        unsigned short a = f2bf(v0[j]);
        hi[j] = a;
        lo[j] = f2bf(v0[j] - bf2f(a));
    }
    *(ushort4v*)(hhi + i) = hi;
    *(ushort4v*)(hlo + i) = lo;
}

// repack W{q,k,v,o,g1} into split-bf16 MFMA B-fragment order:
// frag(m,kc,ct,hilo): 64 lanes x 8 bf16, lane holds B[k=kc*32+(lane>>4)*8+j][n=ct*16+(lane&15)]
__global__ void k_split_w(const float* __restrict__ Wq, const float* __restrict__ Wk,
                          const float* __restrict__ Wv, const float* __restrict__ Wo,
                          const float* __restrict__ Wg1, unsigned short* __restrict__ ws) {
    int t = blockIdx.x * 256 + threadIdx.x;          // grid exact: 5*16384
    int m = t >> 14, r = t & 16383;
    int k = r >> 7, n = r & 127;
    const float* W = (m == 0) ? Wq : (m == 1) ? Wk : (m == 2) ? Wv : (m == 3) ? Wo : Wg1;
    float x = W[k * 128 + n];
    int kc = k >> 5, kin = k & 31, quad = kin >> 3, j = kin & 7;
    int ct = n >> 4, nin = n & 15, lane = quad * 16 + nin;
    unsigned base = ((((unsigned)(m * 4 + kc) * 8 + ct) * 2) * 64 + lane) * 8 + j;
    unsigned short a = f2bf(x);
    ws[base] = a;                                    // hilo=0
    ws[base + 512] = f2bf(x - bf2f(a));              // hilo=1 (+64 lanes*8)
}

// q/k/v via split-bf16 MFMA. q written fp32; k,v packed as bf16 pairs
// (k in lo16, v in hi16) -> single gather array for the edge phase.
__global__ __launch_bounds__(256) void k_qkv_mfma(
    const unsigned short* __restrict__ hhi, const unsigned short* __restrict__ hlo,
    const unsigned short* __restrict__ wsp,
    const float* __restrict__ bq, const float* __restrict__ bk, const float* __restrict__ bv,
    float* __restrict__ q, unsigned* __restrict__ kvp) {
    const int wave = threadIdx.x >> 6, lane = threadIdx.x & 63;
    const int quad = lane >> 4, l15 = lane & 15;
    const int ct0 = wave * 2;
    const int row0 = blockIdx.x * 32;

    floatx4 acc[3][2][2];                            // [mat][ctl][rt]
#pragma unroll
    for (int m = 0; m < 3; ++m)
#pragma unroll
        for (int c = 0; c < 2; ++c)
#pragma unroll
            for (int r = 0; r < 2; ++r) acc[m][c][r] = (floatx4){0.f, 0.f, 0.f, 0.f};

#pragma unroll
    for (int kc = 0; kc < 4; ++kc) {
        short8 ah[2], al[2];
#pragma unroll
        for (int rt = 0; rt < 2; ++rt) {
            int row = row0 + rt * 16 + l15;
            if (row >= N_NODES) row = N_NODES - 1;
            size_t off = (size_t)row * 128 + kc * 32 + quad * 8;
            ah[rt] = *(const short8*)(hhi + off);
            al[rt] = *(const short8*)(hlo + off);
        }
#pragma unroll
        for (int m = 0; m < 3; ++m) {
#pragma unroll
            for (int ctl = 0; ctl < 2; ++ctl) {
                unsigned fb = ((((unsigned)(m * 4 + kc) * 8 + (ct0 + ctl)) * 2) * 64 + lane) * 8;
                short8 bh = *(const short8*)(wsp + fb);
                short8 bl = *(const short8*)(wsp + fb + 512);
#pragma unroll
                for (int rt = 0; rt < 2; ++rt) {
                    acc[m][ctl][rt] = __builtin_amdgcn_mfma_f32_16x16x32_bf16(
                        ah[rt], bh, acc[m][ctl][rt], 0, 0, 0);
                    acc[m][ctl][rt] = __builtin_amdgcn_mfma_f32_16x16x32_bf16(
                        ah[rt], bl, acc[m][ctl][rt], 0, 0, 0);
                    acc[m][ctl][rt] = __builtin_amdgcn_mfma_f32_16x16x32_bf16(
                        al[rt], bh, acc[m][ctl][rt], 0, 0, 0);
                }
            }
        }
    }

#pragma unroll
    for (int ctl = 0; ctl < 2; ++ctl) {
        int col = (ct0 + ctl) * 16 + l15;
        float bq_ = bq[col], bk_ = bk[col], bv_ = bv[col];
#pragma unroll
        for (int rt = 0; rt < 2; ++rt) {
#pragma unroll
            for (int reg = 0; reg < 4; ++reg) {
                int row = row0 + rt * 16 + quad * 4 + reg;
                if (row < N_NODES) {
                    q[(size_t)row * 128 + col] = acc[0][ctl][rt][reg] + bq_;
                    unsigned kb = f2bf(acc[1][ctl][rt][reg] + bk_);
                    unsigned vb = f2bf(acc[2][ctl][rt][reg] + bv_);
                    kvp[(size_t)row * 128 + col] = kb | (vb << 16);
                }
            }
        }
    }
}

// degree histogram
__global__ void k_count(const int* __restrict__ src, int* __restrict__ cnt) {
    int e = blockIdx.x * 256 + threadIdx.x;
    if (e < N_EDGES) atomicAdd(&cnt[src[e]], 1);
}

// hierarchical scan over 50000 counts
__global__ __launch_bounds__(1024) void k_scan1(const int* __restrict__ cnt,
                                                int* __restrict__ loc,
                                                int* __restrict__ bsum, int n) {
    __shared__ int buf[1024];
    int t = threadIdx.x;
    int i = blockIdx.x * 1024 + t;
    int val = (i < n) ? cnt[i] : 0;
    buf[t] = val;
    __syncthreads();
    for (int off = 1; off < 1024; off <<= 1) {
        int a = (t >= off) ? buf[t - off] : 0;
        __syncthreads();
        buf[t] += a;
        __syncthreads();
    }
    if (i < n) loc[i] = buf[t];
    if (t == 1023) bsum[blockIdx.x] = buf[1023];
}

__global__ void k_scan2(int* __restrict__ bsum, int nb) {
    int t = threadIdx.x;
    int v = (t < nb) ? bsum[t] : 0;
    for (int off = 1; off < 64; off <<= 1) {
        int a = __shfl_up(v, off);
        if (t >= off) v += a;
    }
    if (t < nb) bsum[t] = v;
}

__global__ void k_scan3(const int* __restrict__ cnt, const int* __restrict__ loc,
                        const int* __restrict__ bsum,
                        int* __restrict__ rowptr, int* __restrict__ cursor, int n) {
    int i = blockIdx.x * 256 + threadIdx.x;
    if (i < n) {
        int off = (i >= 1024) ? bsum[(i >> 10) - 1] : 0;
        int incl = loc[i] + off;
        rowptr[i + 1] = incl;
        cursor[i] = incl - cnt[i];
    }
    if (i == 0) rowptr[0] = 0;
}

// scatter into CSR order: esd[pos] = (dst, dist^2) as one 8B store
__global__ void k_scatter(const int* __restrict__ src, const int* __restrict__ dst,
                          const float* __restrict__ dist, int* __restrict__ cursor,
                          int2* __restrict__ esd) {
    int e = blockIdx.x * 256 + threadIdx.x;
    if (e < N_EDGES) {
        int pos = atomicAdd(&cursor[src[e]], 1);
        float dd = dist[e];
        esd[pos] = make_int2(dst[e], __float_as_int(dd * dd));
    }
}

// FUSED edge+node: one wave per node, 4-edge batched inner loop for MLP.
// Per edge: ONE gather of the packed bf16 kv row (uint2/lane = cols 2l,2l+1).
// All 4 kv gathers + x gathers issued before any consume -> 4-8 loads in
// flight per wave (vs 1 before). 32-bit gather address math.
__global__ __launch_bounds__(256) void k_edge_node(
    const float* __restrict__ q, const unsigned* __restrict__ kvp,
    const float* __restrict__ x,
    const int2* __restrict__ esd, const int* __restrict__ rowptr,
    const float* __restrict__ Wd, const float* __restrict__ bd,
    unsigned short* __restrict__ hupd_hi, unsigned short* __restrict__ hupd_lo,
    float* __restrict__ disp) {
    const int wave = threadIdx.x >> 6, lane = threadIdx.x & 63;
    const int node = blockIdx.x * 4 + wave;           // grid exact: N/4 blocks
    const int h = lane >> 3, sub = lane & 7;          // head, within-head slot
    const int beg = rowptr[node], end = rowptr[node + 1];

    const float2 qv = *(const float2*)(q + (size_t)node * 128 + 2 * lane);
    const float wdh = Wd[h], bdh = bd[h];
    const bool dal = (sub < 3);
    float xs = dal ? x[node * 3 + sub] : 0.f;
    const unsigned colo = 2 * lane;

    float acc0 = 0.f, acc1 = 0.f, s_own = 0.f, da = 0.f;

    for (int cb = beg; cb < end; cb += 64) {
        int idx = cb + lane;
        int dvec = 0; float d2vec = 0.f;
        if (idx < end) {
            int2 ed = esd[idx];
            dvec = ed.x;
            d2vec = __int_as_float(ed.y);
        }
        int clen = min(64, end - cb);
        int i = 0;
        for (; i + 4 <= clen; i += 4) {
            int di[4]; float dd2[4]; uint2 kv2[4]; float xg[4];
#pragma unroll
            for (int j = 0; j < 4; ++j) {
                di[j]  = __shfl(dvec, i + j);
                dd2[j] = __shfl(d2vec, i + j);
            }
#pragma unroll
            for (int j = 0; j < 4; ++j)
                kv2[j] = *(const uint2*)(kvp + (unsigned)di[j] * 128u + colo);
#pragma unroll
            for (int j = 0; j < 4; ++j)
                xg[j] = dal ? x[(unsigned)di[j] * 3u + sub] : 0.f;
#pragma unroll
            for (int j = 0; j < 4; ++j) {
                float k0 = __builtin_bit_cast(float, kv2[j].x << 16);
                float v0 = __builtin_bit_cast(float, kv2[j].x & 0xFFFF0000u);
                float k1 = __builtin_bit_cast(float, kv2[j].y << 16);
                float v1 = __builtin_bit_cast(float, kv2[j].y & 0xFFFF0000u);
                float p = qv.x * k0 + qv.y * k1;
                p += __shfl_xor(p, 1);
                p += __shfl_xor(p, 2);
                p += __shfl_xor(p, 4);                 // all 8 lanes of head h: full dot
                float w = __expf(p * 0.25f - (dd2[j] * wdh + bdh));
                s_own += w;
                acc0 += v0 * w;
                acc1 += v1 * w;
                da += (xg[j] - xs) * w;                // xs=xg=0 on non-da lanes
            }
        }
        for (; i < clen; ++i) {
            int dij  = __shfl(dvec, i);
            float d2 = __shfl(d2vec, i);
            uint2 kv2 = *(const uint2*)(kvp + (unsigned)dij * 128u + colo);
            float xgj = dal ? x[(unsigned)dij * 3u + sub] : 0.f;
            float k0 = __builtin_bit_cast(float, kv2.x << 16);
            float v0 = __builtin_bit_cast(float, kv2.x & 0xFFFF0000u);
            float k1 = __builtin_bit_cast(float, kv2.y << 16);
            float v1 = __builtin_bit_cast(float, kv2.y & 0xFFFF0000u);
            float p = qv.x * k0 + qv.y * k1;
            p += __shfl_xor(p, 1);
            p += __shfl_xor(p, 2);
            p += __shfl_xor(p, 4);
            float w = __expf(p * 0.25f - (d2 * wdh + bdh));
            s_own += w;
            acc0 += v0 * w;
            acc1 += v1 * w;
            da += (xgj - xs) * w;
        }
    }

    float inva = 1.f / fmaxf(s_own, 1e-9f);
    float o0 = acc0 * inva, o1 = acc1 * inva;
    unsigned short h0 = f2bf(o0), h1 = f2bf(o1);
    unsigned short l0 = f2bf(o0 - bf2f(h0)), l1 = f2bf(o1 - bf2f(h1));
    ((unsigned*)hupd_hi)[(size_t)node * 64 + lane] = (unsigned)h0 | ((unsigned)h1 << 16);
    ((unsigned*)hupd_lo)[(size_t)node * 64 + lane] = (unsigned)l0 | ((unsigned)l1 << 16);

    // disp: da is head h's unnormalized sum for dim=sub (sub<3). Normalize by
    // own head's s, mean over heads (x0.125), then sum across head groups.
    da *= 0.125f * inva;
    da += __shfl_xor(da, 8);
    da += __shfl_xor(da, 16);
    da += __shfl_xor(da, 32);
    if (lane < 3) disp[node * 3 + lane] = da;
}

// fused MFMA epilogue: hout = h + hupd@Wo + bo (GEMM1, split-bf16 MFMA);
// hout staged in per-wave padded LDS (C->A layout transpose);
// GEMM2 = hout@Wg1; gate = tanh(sum_col silu(.)*Wg2); xout = x + gate*disp.
__global__ __launch_bounds__(256) void k_hout_gate(
    const float* __restrict__ h,
    const unsigned short* __restrict__ hupd_hi, const unsigned short* __restrict__ hupd_lo,
    const unsigned short* __restrict__ wsp,
    const float* __restrict__ bo, const float* __restrict__ bg1,
    const float* __restrict__ Wg2, const float* __restrict__ bg2,
    const float* __restrict__ x, const float* __restrict__ disp,
    float* __restrict__ hout, float* __restrict__ xout) {
    __shared__ float hb[4][16 * 132];                 // +4 dword pad per row
    const int wave = threadIdx.x >> 6, lane = threadIdx.x & 63;
    const int quad = lane >> 4, l15 = lane & 15;
    const int row0 = blockIdx.x * 64 + wave * 16;
    float* hbw = hb[wave];

    // ---- GEMM1: hupd @ Wo (m=3) ----
    floatx4 acc[8];
#pragma unroll
    for (int c = 0; c < 8; ++c) acc[c] = (floatx4){0.f, 0.f, 0.f, 0.f};
#pragma unroll
    for (int kc = 0; kc < 4; ++kc) {
        int row = row0 + l15;
        if (row >= N_NODES) row = N_NODES - 1;
        size_t aoff = (size_t)row * 128 + kc * 32 + quad * 8;
        short8 ah = *(const short8*)(hupd_hi + aoff);
        short8 al = *(const short8*)(hupd_lo + aoff);
#pragma unroll
        for (int ct = 0; ct < 8; ++ct) {
            unsigned fb = ((((unsigned)(3 * 4 + kc) * 8 + ct) * 2) * 64 + lane) * 8;
            short8 bh = *(const short8*)(wsp + fb);
            short8 bl = *(const short8*)(wsp + fb + 512);
            acc[ct] = __builtin_amdgcn_mfma_f32_16x16x32_bf16(ah, bh, acc[ct], 0, 0, 0);
            acc[ct] = __builtin_amdgcn_mfma_f32_16x16x32_bf16(ah, bl, acc[ct], 0, 0, 0);
            acc[ct] = __builtin_amdgcn_mfma_f32_16x16x32_bf16(al, bh, acc[ct], 0, 0, 0);
        }
    }

    // epilogue 1: add h + bo, write hout (global) + LDS tile
#pragma unroll
    for (int ct = 0; ct < 8; ++ct) {
        int col = ct * 16 + l15;
        float bias = bo[col];
#pragma unroll
        for (int reg = 0; reg < 4; ++reg) {
            int row = row0 + quad * 4 + reg;
            float val = acc[ct][reg] + bias;
            if (row < N_NODES) {
                val += h[(size_t)row * 128 + col];
                hout[(size_t)row * 128 + col] = val;
            }
            hbw[(quad * 4 + reg) * 132 + col] = val;
        }
    }
    __asm__ volatile("s_waitcnt lgkmcnt(0)" ::: "memory");

    // ---- GEMM2: hout @ Wg1 (m=4), A-frags read from LDS ----
    floatx4 acc2[8];
#pragma unroll
    for (int c = 0; c < 8; ++c) acc2[c] = (floatx4){0.f, 0.f, 0.f, 0.f};
#pragma unroll
    for (int kc = 0; kc < 4; ++kc) {
        const float* ap = hbw + l15 * 132 + kc * 32 + quad * 8;
        float4 f0 = *(const float4*)(ap);
        float4 f1 = *(const float4*)(ap + 4);
        float fv[8] = {f0.x, f0.y, f0.z, f0.w, f1.x, f1.y, f1.z, f1.w};
        short8 ah, al;
#pragma unroll
        for (int j = 0; j < 8; ++j) {
            unsigned short hi = f2bf(fv[j]);
            ah[j] = (short)hi;
            al[j] = (short)f2bf(fv[j] - bf2f(hi));
        }
#pragma unroll
        for (int ct = 0; ct < 8; ++ct) {
            unsigned fb = ((((unsigned)(4 * 4 + kc) * 8 + ct) * 2) * 64 + lane) * 8;
            short8 bh = *(const short8*)(wsp + fb);
            short8 bl = *(const short8*)(wsp + fb + 512);
            acc2[ct] = __builtin_amdgcn_mfma_f32_16x16x32_bf16(ah, bh, acc2[ct], 0, 0, 0);
            acc2[ct] = __builtin_amdgcn_mfma_f32_16x16x32_bf16(ah, bl, acc2[ct], 0, 0, 0);
            acc2[ct] = __builtin_amdgcn_mfma_f32_16x16x32_bf16(al, bh, acc2[ct], 0, 0, 0);
        }
    }

    // epilogue 2: silu * Wg2, reduce cols -> gate -> xout
    float pr[4] = {0.f, 0.f, 0.f, 0.f};
#pragma unroll
    for (int ct = 0; ct < 8; ++ct) {
        int col = ct * 16 + l15;
        float b1 = bg1[col];
        float w2 = Wg2[col];
#pragma unroll
        for (int reg = 0; reg < 4; ++reg) {
            float z = acc2[ct][reg] + b1;
            pr[reg] += (z / (1.f + __expf(-z))) * w2;
        }
    }
#pragma unroll
    for (int off = 1; off < 16; off <<= 1) {
#pragma unroll
        for (int reg = 0; reg < 4; ++reg) pr[reg] += __shfl_xor(pr[reg], off);
    }
    if (l15 == 0) {
        float b2 = bg2[0];
#pragma unroll
        for (int reg = 0; reg < 4; ++reg) {
            int row = row0 + quad * 4 + reg;
            if (row < N_NODES) {
                float g = tanhf(pr[reg] + b2);
#pragma unroll
                for (int dd = 0; dd < 3; ++dd) {
                    int oo = row * 3 + dd;
                    xout[oo] = x[oo] + g * disp[oo];
                }
            }
        }
    }
}

extern "C" void kernel_launch(void* const* d_in, const int* in_sizes, int n_in,
                              void* d_out, int out_size, void* d_ws, size_t ws_size,
                              hipStream_t stream) {
    const float* h    = (const float*)d_in[0];
    const float* x    = (const float*)d_in[1];
    const int*   src  = (const int*)d_in[2];
    const int*   dst  = (const int*)d_in[3];
    const float* dist = (const float*)d_in[4];
    const float* Wq = (const float*)d_in[5];  const float* bq = (const float*)d_in[6];
    const float* Wk = (const float*)d_in[7];  const float* bk = (const float*)d_in[8];
    const float* Wv = (const float*)d_in[9];  const float* bv = (const float*)d_in[10];
    const float* Wo = (const float*)d_in[11]; const float* bo = (const float*)d_in[12];
    const float* Wd = (const float*)d_in[13]; const float* bd = (const float*)d_in[14];
    const float* Wg1 = (const float*)d_in[15]; const float* bg1 = (const float*)d_in[16];
    const float* Wg2 = (const float*)d_in[17]; const float* bg2 = (const float*)d_in[18];

    float* ws    = (float*)d_ws;
    float* q     = ws + OFF_Q;
    unsigned* kvp = (unsigned*)(ws + OFF_KV);
    float* disp  = ws + OFF_DISP;
    int* cnt     = (int*)(ws + OFF_CNT);
    int* rowptr  = (int*)(ws + OFF_ROWPTR);
    int* cursor  = (int*)(ws + OFF_CURSOR);
    int2* esd    = (int2*)(ws + OFF_ESD);
    unsigned short* hhi = (unsigned short*)(ws + OFF_HHI);
    unsigned short* hlo = (unsigned short*)(ws + OFF_HLO);
    unsigned short* wsp = (unsigned short*)(ws + OFF_WSPLIT);
    // scan scratch in q region, consumed before k_qkv_mfma writes q
    int* loc    = (int*)(ws + OFF_Q);
    int* bsum   = (int*)(ws + OFF_Q + 500000u);
    // hupd reuses hhi/hlo regions (dead after k_qkv_mfma)
    unsigned short* hupd_hi = (unsigned short*)(ws + OFF_HHI);
    unsigned short* hupd_lo = (unsigned short*)(ws + OFF_HLO);
    float* hout = (float*)d_out;
    float* xout = hout + (size_t)N_NODES * HIDDEN;

    const int nscan = (N_NODES + 1023) / 1024;    // 49

    k_split_h<<<6250, 256, 0, stream>>>(h, hhi, hlo);
    k_split_w<<<320, 256, 0, stream>>>(Wq, Wk, Wv, Wo, Wg1, wsp);
    k_zero_int<<<(N_NODES + 255) / 256, 256, 0, stream>>>(cnt, N_NODES);
    k_count<<<(N_EDGES + 255) / 256, 256, 0, stream>>>(src, cnt);
    k_scan1<<<nscan, 1024, 0, stream>>>(cnt, loc, bsum, N_NODES);
    k_scan2<<<1, 64, 0, stream>>>(bsum, nscan);
    k_scan3<<<(N_NODES + 255) / 256, 256, 0, stream>>>(cnt, loc, bsum, rowptr, cursor, N_NODES);
    k_scatter<<<(N_EDGES + 255) / 256, 256, 0, stream>>>(src, dst, dist, cursor, esd);
    k_qkv_mfma<<<(N_NODES + 31) / 32, 256, 0, stream>>>(hhi, hlo, wsp, bq, bk, bv, q, kvp);
    k_edge_node<<<N_NODES / 4, 256, 0, stream>>>(q, kvp, x, esd, rowptr,
                                                 Wd, bd, hupd_hi, hupd_lo, disp);
    k_hout_gate<<<(N_NODES + 63) / 64, 256, 0, stream>>>(h, hupd_hi, hupd_lo, wsp,
                                                         bo, bg1, Wg2, bg2,
                                                         x, disp, hout, xout);
}